// Round 12
// baseline (1595.941 us; speedup 1.0000x reference)
//
#include <hip/hip_runtime.h>

// ---------------------------------------------------------------------------
// VQ-VAE forward, round 21: r19 base (1338us) + co x16 widening in
// conv1/conv2/conv3 (16 f64 acc/thread; per-ci issue = 1024 FMA-cyc per 16
// loads -> overhead ~6%, 2-wave/SIMD alternation covers load latency).
// FMA order per output bitwise-preserved (ci asc, tp asc). r20 block-split
// reverted (combine traffic ate the win). Decoder f16-MFMA (r19).
//
// d_out (float32): recon[786432] | commit_loss[1] | indices[16384]
//
// Workspace (BYTE offsets), ~86.6 MB peak:
#define OFF_A     ((size_t)0)          // h1p / Ap / d2pH(f16)
#define OFF_BINFO ((size_t)8388608)
#define OFF_B     ((size_t)34611200)   // h2p / qH(f16)
#define OFF_C     ((size_t)43532288)   // xpad / h3 / d1pH(f16)
#define OFF_D     ((size_t)52453376)   // zf
#define OFF_E     ((size_t)69230592)   // Bp / PC
#define OFF_ZN    ((size_t)81813504)
#define OFF_CN    ((size_t)81879040)
#define OFF_IDX   ((size_t)81911808)
#define OFF_ACC   ((size_t)81977344)
#define OFF_WR2   ((size_t)81977600)   // f16 convt2 weights 512KB, then whd1 f16 288KB
#define OFF_WHD1  ((size_t)82501888)   // = OFF_WR2 + 524288
#define OFF_WR3   ((size_t)83026176)
#define OFF_QWT   ((size_t)83050752)
#define OFF_WD2   ((size_t)83181824)   // f64 conv2 weights, 2 MB
#define OFF_WD3   ((size_t)85278976)   // f64 conv3 weights, 1.18 MB
#define OFF_WD1   ((size_t)86458624)   // f64 conv1 weights, 48 KB

#define VQ_MARGIN 1.2e-4f
#define LDSS 40

typedef __attribute__((ext_vector_type(8))) _Float16 f16x8;
typedef __attribute__((ext_vector_type(4))) float f32x4;

// ---------- helpers ----------
__device__ __forceinline__ unsigned fkey(float f) {
  unsigned u = __float_as_uint(f);
  return (u & 0x80000000u) ? ~u : (u | 0x80000000u);
}
__device__ __forceinline__ float funkey(unsigned k) {
  unsigned u = (k & 0x80000000u) ? (k ^ 0x80000000u) : ~k;
  return __uint_as_float(u);
}
__device__ __forceinline__ void padzero_img(float* base, int S, int t) {
  for (int e = t; e < 4 * S - 4; e += 256) {
    int rr, cc;
    if (e < S) { rr = 0; cc = e; }
    else if (e < 2 * S) { rr = S - 1; cc = e - S; }
    else { rr = ((e - 2 * S) >> 1) + 1; cc = (e & 1) ? (S - 1) : 0; }
    base[rr * S + cc] = 0.0f;
  }
}
__device__ __forceinline__ void padzero_img_h(_Float16* base, int S, int t) {
  for (int e = t; e < 4 * S - 4; e += 256) {
    int rr, cc;
    if (e < S) { rr = 0; cc = e; }
    else if (e < 2 * S) { rr = S - 1; cc = e - S; }
    else { rr = ((e - 2 * S) >> 1) + 1; cc = (e & 1) ? (S - 1) : 0; }
    base[rr * S + cc] = (_Float16)0.0f;
  }
}

// ---------- ONE prep kernel: weight reshapes/widens + encoder pad zeros ----------
__global__ __launch_bounds__(256) void prep_k(
    const float* __restrict__ dtw2, _Float16* __restrict__ wh2,
    const float* __restrict__ dtw3, float* __restrict__ wr3,
    const float* __restrict__ qw,   float* __restrict__ qwT,
    const float* __restrict__ ew2,  double* __restrict__ wd2,
    const float* __restrict__ ew3,  double* __restrict__ wd3,
    const float* __restrict__ ew1,  double* __restrict__ wd1,
    const float* __restrict__ dw1,  _Float16* __restrict__ whd1,
    float* __restrict__ xpad, float* __restrict__ h1p, float* __restrict__ h2p) {
  int b = blockIdx.x, t = threadIdx.x;
  if (b < 256) {          // wresh2 -> f16 [cls][co][ci][4], k-order {d1,d0,d3,d2}
    int tid = b * 256 + t;
    int ci = tid & 127, co = (tid >> 7) & 127, cls = tid >> 14;
    int kh0 = 1 - (cls >> 1), kw0 = 1 - (cls & 1);
    const float* s = dtw2 + ((size_t)ci * 128 + co) * 16;
    _Float16* d = wh2 + (size_t)tid * 4;
    float d0 = s[kh0 * 4 + kw0];       float d1v = s[kh0 * 4 + kw0 + 2];
    float d2v = s[(kh0 + 2) * 4 + kw0]; float d3v = s[(kh0 + 2) * 4 + kw0 + 2];
    d[0] = (_Float16)d1v; d[1] = (_Float16)d0;
    d[2] = (_Float16)d3v; d[3] = (_Float16)d2v;
  } else if (b < 262) {                // wresh3
    int tid = (b - 256) * 256 + t;
    if (tid < 1536) {
      int ci = tid & 127, co = (tid >> 7) % 3, cls = tid / 384;
      int kh0 = 1 - (cls >> 1), kw0 = 1 - (cls & 1);
      const float* s = dtw3 + ((size_t)ci * 3 + co) * 16;
      float* d = wr3 + (size_t)tid * 4;
      d[0] = s[kh0 * 4 + kw0];       d[1] = s[kh0 * 4 + kw0 + 2];
      d[2] = s[(kh0 + 2) * 4 + kw0]; d[3] = s[(kh0 + 2) * 4 + kw0 + 2];
    }
  } else if (b < 390) {                // qwT
    int tid = (b - 262) * 256 + t;
    int co = tid & 255, ci = tid >> 8;
    qwT[(size_t)ci * 256 + co] = qw[(size_t)co * 128 + ci];
  } else if (b < 1414) {               // widen ew2
    int tid = (b - 390) * 256 + t;
    wd2[tid] = (double)ew2[tid];
  } else if (b < 1990) {               // widen ew3
    int tid = (b - 1414) * 256 + t;
    wd3[tid] = (double)ew3[tid];
  } else if (b < 2014) {               // widen ew1
    int tid = (b - 1990) * 256 + t;
    wd1[tid] = (double)ew1[tid];
  } else if (b < 2026) {               // pad-zero xpad (12 imgs of 258)
    padzero_img(xpad + (size_t)(b - 2014) * 66564, 258, t);
  } else if (b < 2538) {               // pad-zero h1p (512 imgs of 130)
    padzero_img(h1p + (size_t)(b - 2026) * 16900, 130, t);
  } else if (b < 3050) {               // pad-zero h2p (512 imgs of 66)
    padzero_img(h2p + (size_t)(b - 2538) * 4356, 66, t);
  } else {                             // whd1: f16 [co][k], k = tap*128 + ci
    int tid = (b - 3050) * 256 + t;    // 576 blocks = 147456 exact
    int co = tid / 1152, k = tid - co * 1152;
    int tap = k >> 7, ci = k & 127;
    whd1[tid] = (_Float16)dw1[((size_t)co * 128 + ci) * 9 + tap];
  }
}

// ---------- pad-copy x into [4][3][258][258] ----------
__global__ __launch_bounds__(256) void padx_k(const float* __restrict__ x,
                                              float* __restrict__ xp) {
  int tid = blockIdx.x * 256 + threadIdx.x;
  int wo = tid & 255, ho = (tid >> 8) & 255, c = tid >> 16;
  xp[((size_t)c * 258 + ho + 1) * 258 + wo + 1] = x[tid];
}

// ---------- enc conv1: k=4 s=2 + ReLU, 3ci, co x16, f64 weights ----------
__global__ __launch_bounds__(256) void conv1_k(
    const float* __restrict__ xp, const double* __restrict__ wd,
    const float* __restrict__ bias, float* __restrict__ h1p) {
  int b = blockIdx.x;
  int chunk = b & 63, cog = (b >> 6) & 7, n = b >> 9;
  int t = threadIdx.x;
  int wo = t & 127, ho = chunk * 2 + (t >> 7);
  int co0 = cog * 16;
  const float* xb = xp + (size_t)n * 3 * 66564 + (size_t)(2 * ho) * 258 + 2 * wo;
  double acc[16] = {};
  for (int ci = 0; ci < 3; ++ci) {
    const float* xc = xb + (size_t)ci * 66564;
    float cf[16];
#pragma unroll
    for (int kh = 0; kh < 4; ++kh)
#pragma unroll
      for (int kw = 0; kw < 4; ++kw) cf[kh * 4 + kw] = xc[kh * 258 + kw];
    const double* wp = wd + (size_t)co0 * 48 + ci * 16;
#pragma unroll
    for (int tp = 0; tp < 16; ++tp) {
      double xd = (double)cf[tp];
#pragma unroll
      for (int cc = 0; cc < 16; ++cc)
        acc[cc] = fma(xd, wp[(size_t)cc * 48 + tp], acc[cc]);
    }
  }
#pragma unroll
  for (int cc = 0; cc < 16; ++cc) {
    float r = (float)((double)bias[co0 + cc] + acc[cc]);
    h1p[(((size_t)n * 128 + co0 + cc) * 130 + ho + 1) * 130 + wo + 1] = fmaxf(r, 0.0f);
  }
}

// ---------- enc conv2: k=4 s=2 + ReLU, co x16, float2 loads ----------
__global__ __launch_bounds__(256) void conv2_k(
    const float* __restrict__ h1p, const double* __restrict__ wd,
    const float* __restrict__ bias, float* __restrict__ h2p) {
  int b = blockIdx.x;
  int chunk = b & 15, cog = (b >> 4) & 7, n = b >> 7;
  int t = threadIdx.x;
  int wo = t & 63, ho = chunk * 4 + (t >> 6);
  int co0 = cog * 16;
  const float* xb = h1p + (size_t)n * 128 * 16900 + (size_t)(2 * ho) * 130 + 2 * wo;
  double acc[16] = {};
  for (int ci = 0; ci < 128; ++ci) {
    const float* xc = xb + (size_t)ci * 16900;
    float cf[16];
#pragma unroll
    for (int kh = 0; kh < 4; ++kh) {
      float2 p0 = *(const float2*)(xc + kh * 130);
      float2 p1 = *(const float2*)(xc + kh * 130 + 2);
      cf[kh * 4 + 0] = p0.x; cf[kh * 4 + 1] = p0.y;
      cf[kh * 4 + 2] = p1.x; cf[kh * 4 + 3] = p1.y;
    }
    const double* wp = wd + (size_t)co0 * 2048 + ci * 16;
#pragma unroll
    for (int tp = 0; tp < 16; ++tp) {
      double xd = (double)cf[tp];
#pragma unroll
      for (int cc = 0; cc < 16; ++cc)
        acc[cc] = fma(xd, wp[(size_t)cc * 2048 + tp], acc[cc]);
    }
  }
#pragma unroll
  for (int cc = 0; cc < 16; ++cc) {
    float r = (float)((double)bias[co0 + cc] + acc[cc]);
    h2p[(((size_t)n * 128 + co0 + cc) * 66 + ho + 1) * 66 + wo + 1] = fmaxf(r, 0.0f);
  }
}

// ---------- enc conv3: k=3 s=1 (no relu), co x16, f64 weights ----------
__global__ __launch_bounds__(256) void conv3_k(
    const float* __restrict__ h2p, const double* __restrict__ wd,
    const float* __restrict__ bias, float* __restrict__ h3) {
  int b = blockIdx.x;
  int chunk = b & 15, cog = (b >> 4) & 7, n = b >> 7;
  int t = threadIdx.x;
  int wo = t & 63, ho = chunk * 4 + (t >> 6);
  int co0 = cog * 16;
  const float* xb = h2p + (size_t)n * 128 * 4356 + (size_t)ho * 66 + wo;
  double acc[16] = {};
  for (int ci = 0; ci < 128; ++ci) {
    const float* xc = xb + (size_t)ci * 4356;
    float cf[9];
#pragma unroll
    for (int kh = 0; kh < 3; ++kh)
#pragma unroll
      for (int kw = 0; kw < 3; ++kw) cf[kh * 3 + kw] = xc[kh * 66 + kw];
    const double* wp = wd + (size_t)co0 * 1152 + ci * 9;
#pragma unroll
    for (int tp = 0; tp < 9; ++tp) {
      double xd = (double)cf[tp];
#pragma unroll
      for (int cc = 0; cc < 16; ++cc)
        acc[cc] = fma(xd, wp[(size_t)cc * 1152 + tp], acc[cc]);
    }
  }
#pragma unroll
  for (int cc = 0; cc < 16; ++cc)
    h3[(((size_t)n * 128 + co0 + cc) << 12) + (ho << 6) + wo] =
        (float)((double)bias[co0 + cc] + acc[cc]);
}

// ---------- 1x1 conv 128->256 fused: zf + Ap(f16) + znorm ----------
__global__ __launch_bounds__(256) void qconv_z_k(
    const float* __restrict__ h3, const float* __restrict__ wT,
    const float* __restrict__ bias, float* __restrict__ zf,
    _Float16* __restrict__ Ap, float* __restrict__ znb) {
  __shared__ double wsum[4];
  int p  = blockIdx.x;
  int co = threadIdx.x;
  int n  = p >> 12;
  int hw = p & 4095;
  const float* xp = h3 + ((size_t)n * 128) * 4096 + hw;
  double a[4] = {0.0, 0.0, 0.0, 0.0};
  for (int ci = 0; ci < 128; ci += 4) {
#pragma unroll
    for (int u = 0; u < 4; ++u) {
      float xv = xp[(size_t)(ci + u) * 4096];
      a[u] = fma((double)xv, (double)wT[(size_t)(ci + u) * 256 + co], a[u]);
    }
  }
  double acc = (double)bias[co] + ((a[0] + a[1]) + (a[2] + a[3]));
  float zv = (float)acc;
  zf[(size_t)p * 256 + co] = zv;
  Ap[(size_t)p * 256 + co] = (_Float16)zv;
  float xx = zv * zv;          // elementwise square op: fp32-rounded
  double s = (double)xx;       // sum op: f64-exact, rounded once
#pragma unroll
  for (int off = 32; off > 0; off >>= 1) s += __shfl_down(s, off, 64);
  if ((co & 63) == 0) wsum[co >> 6] = s;
  __syncthreads();
  if (co == 0) znb[p] = (float)((wsum[0] + wsum[1]) + (wsum[2] + wsum[3]));
}

// ---------- codebook prep fused: Bp(f16 x512) + cnorm ----------
__global__ __launch_bounds__(256) void cbprep_k(
    const float* __restrict__ cb, _Float16* __restrict__ Bp,
    float* __restrict__ cnb) {
  __shared__ double wsum[4];
  int k = blockIdx.x, t = threadIdx.x;
  float c = cb[(size_t)k * 256 + t];
  Bp[(size_t)k * 256 + t] = (_Float16)(c * 512.0f);
  float xx = c * c;
  double s = (double)xx;
#pragma unroll
  for (int off = 32; off > 0; off >>= 1) s += __shfl_down(s, off, 64);
  if ((t & 63) == 0) wsum[t >> 6] = s;
  __syncthreads();
  if (t == 0) cnb[k] = (float)((wsum[0] + wsum[1]) + (wsum[2] + wsum[3]));
}

// ---------- VQ filter GEMM: 128x128 tile, 16x16x32 f16 MFMA, K=256 ----------
__global__ __launch_bounds__(256, 2) void vq_gemm_k(
    const _Float16* __restrict__ Ah, const _Float16* __restrict__ Bh,
    const float* __restrict__ cnArr, int4* __restrict__ binfo) {
  __shared__ __align__(16) _Float16 As[128 * LDSS];
  __shared__ __align__(16) _Float16 Bs[128 * LDSS];
  __shared__ unsigned loc[128];
  __shared__ int cnt_sh[128];
  __shared__ int cand_sh[128][2];
  const int t = threadIdx.x;
  const int w = t >> 6, L = t & 63;
  const int mb = blockIdx.x >> 6;
  const int nb = blockIdx.x & 63;
  const int m0 = mb << 7, n0 = nb << 7;
  if (t < 128) { loc[t] = 0xFFFFFFFFu; cnt_sh[t] = 0; }
  f32x4 acc[4][4] = {};
  const int wr = (w >> 1) << 6, wc = (w & 1) << 6;
  const int srow = L >> 2, kg = L & 3;
  const int q = L >> 4, ln = L & 15;
  for (int kk = 0; kk < 256; kk += 32) {
    __syncthreads();
#pragma unroll
    for (int c = 0; c < 2; ++c) {
      const int row = (w << 5) + (c << 4) + srow;
      const f16x8 av = *(const f16x8*)(Ah + (size_t)(m0 + row) * 256 + kk + kg * 8);
      *(f16x8*)(&As[row * LDSS + kg * 8]) = av;
      const f16x8 bv = *(const f16x8*)(Bh + (size_t)(n0 + row) * 256 + kk + kg * 8);
      *(f16x8*)(&Bs[row * LDSS + kg * 8]) = bv;
    }
    __syncthreads();
    f16x8 af[4], bf[4];
#pragma unroll
    for (int i = 0; i < 4; ++i)
      af[i] = *(const f16x8*)(&As[(wr + 16 * i + ln) * LDSS + q * 8]);
#pragma unroll
    for (int j = 0; j < 4; ++j)
      bf[j] = *(const f16x8*)(&Bs[(wc + 16 * j + ln) * LDSS + q * 8]);
#pragma unroll
    for (int i = 0; i < 4; ++i)
#pragma unroll
      for (int j = 0; j < 4; ++j)
        acc[i][j] = __builtin_amdgcn_mfma_f32_16x16x32_f16(af[i], bf[j], acc[i][j], 0, 0, 0);
  }
  float cnv[4];
#pragma unroll
  for (int j = 0; j < 4; ++j) cnv[j] = cnArr[n0 + wc + 16 * j + ln];
#pragma unroll
  for (int i = 0; i < 4; ++i)
#pragma unroll
    for (int r = 0; r < 4; ++r) {
      float mn = 3.4e38f;
#pragma unroll
      for (int j = 0; j < 4; ++j)
        mn = fminf(mn, fmaf(-0.00390625f, acc[i][j][r], cnv[j]));
      // min-reduce across the 16 lanes sharing this rib, then ONE atomic
#pragma unroll
      for (int s = 1; s < 16; s <<= 1)
        mn = fminf(mn, __shfl_xor(mn, s, 64));
      if (ln == 0) atomicMin(&loc[wr + 16 * i + 4 * q + r], fkey(mn));
    }
  __syncthreads();
#pragma unroll
  for (int i = 0; i < 4; ++i)
#pragma unroll
    for (int r = 0; r < 4; ++r) {
      const int rib = wr + 16 * i + 4 * q + r;
      const float thr = funkey(loc[rib]) + VQ_MARGIN;
#pragma unroll
      for (int j = 0; j < 4; ++j) {
        float s = fmaf(-0.00390625f, acc[i][j][r], cnv[j]);
        if (s <= thr) {
          int slot = atomicAdd(&cnt_sh[rib], 1);
          if (slot < 2) cand_sh[rib][slot] = n0 + wc + 16 * j + ln;
        }
      }
    }
  __syncthreads();
  if (t < 128) {
    int4 v;
    v.x = cnt_sh[t];
    v.y = cand_sh[t][0];
    v.z = cand_sh[t][1];
    v.w = (int)__float_as_uint(funkey(loc[t]));
    binfo[(size_t)(m0 + t) * 64 + nb] = v;
  }
}

// ---------- VQ final: binfo-pruned argmin (also zeroes accum for commit) ----------
__global__ __launch_bounds__(256) void vq_phase3_k(
    const float* __restrict__ zf, const float* __restrict__ cb,
    const float* __restrict__ znArr, const float* __restrict__ cnArr,
    const int4* __restrict__ binfo, int* __restrict__ idxOut,
    float* __restrict__ accum) {
  if (blockIdx.x == 0 && threadIdx.x == 0) *accum = 0.0f;
  const int lane = threadIdx.x & 63;
  const int r = blockIdx.x * 4 + (threadIdx.x >> 6);
  const float* zr = zf + (size_t)r * 256;
  double z4[4];
#pragma unroll
  for (int j = 0; j < 4; ++j) z4[j] = (double)zr[lane + (j << 6)];
  const float znr = znArr[r];
  int4 b = binfo[(size_t)r * 64 + lane];
  float bv = __uint_as_float((unsigned)b.w);
  float m = bv;
#pragma unroll
  for (int off = 32; off > 0; off >>= 1) m = fminf(m, __shfl_down(m, off, 64));
  m = __shfl(m, 0, 64);
  const float thr = m + VQ_MARGIN;
  unsigned long long mask = __ballot(bv <= thr);
  float bestd = 3.4e38f;
  int bestk = 0x7fffffff;
  while (mask) {
    const int nb = (int)__builtin_ctzll(mask);
    mask &= mask - 1;
    const int c  = __shfl(b.x, nb, 64);
    const int k0 = __shfl(b.y, nb, 64);
    const int k1 = __shfl(b.z, nb, 64);
    const int nsc = (c <= 2) ? c : 128;
    for (int s2 = 0; s2 < nsc; ++s2) {
      const int k = (c <= 2) ? (s2 == 0 ? k0 : k1) : (nb * 128 + s2);
      const float* ck = cb + (size_t)k * 256;
      double p = 0.0;
#pragma unroll
      for (int j = 0; j < 4; ++j)
        p = fma(z4[j], (double)ck[lane + (j << 6)], p);
#pragma unroll
      for (int off = 32; off > 0; off >>= 1) p += __shfl_down(p, off, 64);
      if (lane == 0) {
        float mm2 = (float)(2.0 * p);
        float t1 = znr + cnArr[k];
        float d = t1 - mm2;
        if (d < bestd || (d == bestd && k < bestk)) { bestd = d; bestk = k; }
      }
    }
  }
  if (lane == 0) idxOut[r] = bestk;
}

// ---------- commit loss partials + indices-as-float output ----------
__global__ __launch_bounds__(256) void commit_k(
    const float* __restrict__ zf, const float* __restrict__ cb,
    const int* __restrict__ idxArr, float* __restrict__ accum,
    float* __restrict__ outIdxF) {
  __shared__ float wsum[4];
  const int p = blockIdx.x;
  const int t = threadIdx.x;
  const int k = idxArr[p];
  float d = cb[(size_t)k * 256 + t] - zf[(size_t)p * 256 + t];
  float v = d * d;
#pragma unroll
  for (int off = 32; off > 0; off >>= 1) v += __shfl_down(v, off, 64);
  if ((t & 63) == 0) wsum[t >> 6] = v;
  __syncthreads();
  if (t == 0) {
    atomicAdd(accum, wsum[0] + wsum[1] + wsum[2] + wsum[3]);
    outIdxF[p] = (float)k;
  }
}

// ---------- projected codebook PC[k][co] = sum_ci cb[k][ci]*pw[co][ci] ----------
__global__ __launch_bounds__(256) void pc_k(const float* __restrict__ cb,
                                            const float* __restrict__ pw,
                                            float* __restrict__ PC) {
  int tid = blockIdx.x * 256 + threadIdx.x;
  int co = tid & 127, k = tid >> 7;
  const float* c = cb + (size_t)k * 256;
  const float* w = pw + (size_t)co * 256;
  float a0 = 0.0f, a1 = 0.0f, a2 = 0.0f, a3 = 0.0f;
  for (int ci = 0; ci < 256; ci += 4) {
    a0 = fmaf(c[ci], w[ci], a0);
    a1 = fmaf(c[ci + 1], w[ci + 1], a1);
    a2 = fmaf(c[ci + 2], w[ci + 2], a2);
    a3 = fmaf(c[ci + 3], w[ci + 3], a3);
  }
  PC[tid] = (a0 + a1) + (a2 + a3);
}

// ---------- decoder pad zeros (qH f16: 66; d1pH f16: 66; d2pH f16: 130) ----------
__global__ __launch_bounds__(256) void padzero_dec_k(
    _Float16* __restrict__ qH, _Float16* __restrict__ d1pH,
    _Float16* __restrict__ d2pH) {
  int b = blockIdx.x, t = threadIdx.x;
  if (b < 512)       padzero_img_h(qH + (size_t)b * 4356, 66, t);
  else if (b < 1024) padzero_img_h(d1pH + (size_t)(b - 512) * 4356, 66, t);
  else               padzero_img_h(d2pH + (size_t)(b - 1024) * 16900, 130, t);
}

// ---------- q = gather(PC, idx) + bias -> f16 padded NCHW [66][66] ----------
__global__ __launch_bounds__(256) void gather_pc_k(
    const float* __restrict__ PC, const int* __restrict__ idxArr,
    const float* __restrict__ pb, _Float16* __restrict__ qH) {
  int tid = blockIdx.x * 256 + threadIdx.x;
  int hw = tid & 4095;
  int co = (tid >> 12) & 127;
  int n  = tid >> 19;
  int p  = (n << 12) + hw;
  int h = hw >> 6, w2 = hw & 63;
  qH[(((size_t)n * 128 + co) * 66 + h + 1) * 66 + w2 + 1] =
      (_Float16)(PC[(size_t)idxArr[p] * 128 + co] + pb[co]);
}

// ---------- dec conv1: f16 MFMA implicit GEMM (16co x 16px, K=1152) ----------
__global__ __launch_bounds__(256) void dconv1_k(
    const _Float16* __restrict__ qH, const _Float16* __restrict__ wa,
    const float* __restrict__ bias, _Float16* __restrict__ d1pH) {
  int b = blockIdx.x;
  int ho = b & 63, cog = (b >> 6) & 7, n = b >> 9;
  int t = threadIdx.x;
  int wv = t >> 6, l = t & 63;
  int q = l >> 4, ln = l & 15;
  int wo0 = wv << 4;
  const unsigned short* qb = (const unsigned short*)qH + (size_t)n * 128 * 4356;
  const _Float16* ap = wa + (size_t)(cog * 16 + ln) * 1152 + q * 8;
  f32x4 acc = {0.0f, 0.0f, 0.0f, 0.0f};
#pragma unroll
  for (int s = 0; s < 36; ++s) {
    const int tap = s >> 2, dh = tap / 3, dw = tap % 3;
    const int cig = ((s & 3) << 5) + (q << 3);
    const unsigned short* bp =
        qb + (size_t)cig * 4356 + (ho + dh) * 66 + wo0 + ln + dw;
    unsigned v0 = bp[0],        v1 = bp[4356];
    unsigned v2 = bp[2 * 4356], v3 = bp[3 * 4356];
    unsigned v4 = bp[4 * 4356], v5 = bp[5 * 4356];
    unsigned v6 = bp[6 * 4356], v7 = bp[7 * 4356];
    union { unsigned u[4]; f16x8 h; } bb;
    bb.u[0] = v0 | (v1 << 16);
    bb.u[1] = v2 | (v3 << 16);
    bb.u[2] = v4 | (v5 << 16);
    bb.u[3] = v6 | (v7 << 16);
    const f16x8 af = *(const f16x8*)(ap + s * 32);
    acc = __builtin_amdgcn_mfma_f32_16x16x32_f16(af, bb.h, acc, 0, 0, 0);
  }
#pragma unroll
  for (int r = 0; r < 4; ++r) {
    int co = (cog << 4) + (q << 2) + r;
    d1pH[(((size_t)n * 128 + co) * 66 + ho + 1) * 66 + wo0 + ln + 1] =
        (_Float16)fmaxf(bias[co] + acc[r], 0.0f);
  }
}

// ---------- convt2: f16 MFMA implicit GEMM (16co x 16px tiles, K=512) ----------
__global__ __launch_bounds__(256) void convt2_k(
    const _Float16* __restrict__ xh, const _Float16* __restrict__ wh,
    const float* __restrict__ bias, _Float16* __restrict__ y) {
  int b = blockIdx.x;
  int i = b & 63, cog = (b >> 6) & 7, cls = (b >> 9) & 3, n = b >> 11;
  int cph = cls >> 1, cpw = cls & 1;
  int t = threadIdx.x;
  int wv = t >> 6, l = t & 63;
  int q = l >> 4, ln = l & 15;
  int wb = (wv << 4) + ln;
  int co0 = cog << 4;
  int r0 = i + 1 + cph, r1 = r0 - 1;
  int c1 = wb + cpw;
  int o0 = r0 * 66 + c1, o1 = r1 * 66 + c1;
  const unsigned short* xb =
      (const unsigned short*)xh + (size_t)n * 128 * 4356 + (size_t)(q * 2) * 4356;
  const _Float16* ap = wh + (size_t)(cls * 128 + co0 + ln) * 512 + q * 8;
  f32x4 acc = {0.0f, 0.0f, 0.0f, 0.0f};
  for (int s = 0; s < 16; ++s) {
    const unsigned short* pa = xb + (size_t)(s * 8) * 4356;
    const unsigned short* pb2 = pa + 4356;
    unsigned v0 = pa[o0], v1 = pa[o0 + 1];
    unsigned v2 = pa[o1], v3 = pa[o1 + 1];
    unsigned v4 = pb2[o0], v5 = pb2[o0 + 1];
    unsigned v6 = pb2[o1], v7 = pb2[o1 + 1];
    union { unsigned u[4]; f16x8 h; } bb;
    bb.u[0] = v0 | (v1 << 16);
    bb.u[1] = v2 | (v3 << 16);
    bb.u[2] = v4 | (v5 << 16);
    bb.u[3] = v6 | (v7 << 16);
    const f16x8 af = *(const f16x8*)(ap + s * 32);
    acc = __builtin_amdgcn_mfma_f32_16x16x32_f16(af, bb.h, acc, 0, 0, 0);
  }
  int ho = 2 * i + cph, wo = 2 * wb + cpw;
#pragma unroll
  for (int r = 0; r < 4; ++r) {
    int co = co0 + q * 4 + r;
    y[(((size_t)n * 128 + co) * 130 + ho + 1) * 130 + wo + 1] =
        (_Float16)fmaxf(bias[co] + acc[r], 0.0f);
  }
}

// ---------- convt3: parity-specialized, 3 co/thread, f16 input ----------
__global__ __launch_bounds__(256) void convt3_k(
    const _Float16* __restrict__ xh, const float* __restrict__ wr,
    const float* __restrict__ bias, float* __restrict__ y,
    const float* __restrict__ accum, float* __restrict__ outLoss) {
  int b = blockIdx.x;
  if (b == 0 && threadIdx.x == 0) *outLoss = *accum * (1.0f / 4194304.0f);
  int chunk = b & 63, cls = (b >> 6) & 3, n = b >> 8;
  int cph = cls >> 1, cpw = cls & 1;
  int t = threadIdx.x;
  int wb = t & 127, i = chunk * 2 + (t >> 7);
  int ho = 2 * i + cph, wo = 2 * wb + cpw;
  int r0 = i + 1 + cph, r1 = r0 - 1;
  int c0 = wb + 1 + cpw, c1 = c0 - 1;
  const _Float16* xb = xh + (size_t)n * 128 * 16900;
  float acc[3] = {0.0f, 0.0f, 0.0f};
  for (int ci = 0; ci < 128; ++ci) {
    const _Float16* xc = xb + (size_t)ci * 16900;
    float x00 = (float)xc[r0 * 130 + c0], x01 = (float)xc[r0 * 130 + c1];
    float x10 = (float)xc[r1 * 130 + c0], x11 = (float)xc[r1 * 130 + c1];
#pragma unroll
    for (int cc = 0; cc < 3; ++cc) {
      const float* w4 = wr + (((size_t)cls * 3 + cc) * 128 + ci) * 4;
      acc[cc] = fmaf(x00, w4[0], acc[cc]);
      acc[cc] = fmaf(x01, w4[1], acc[cc]);
      acc[cc] = fmaf(x10, w4[2], acc[cc]);
      acc[cc] = fmaf(x11, w4[3], acc[cc]);
    }
  }
#pragma unroll
  for (int cc = 0; cc < 3; ++cc)
    y[(((size_t)n * 3 + cc) << 16) + (ho << 8) + wo] = bias[cc] + acc[cc];
}

// ---------------------------------------------------------------------------
extern "C" void kernel_launch(void* const* d_in, const int* in_sizes, int n_in,
                              void* d_out, int out_size, void* d_ws, size_t ws_size,
                              hipStream_t stream) {
  const float* x    = (const float*)d_in[0];
  const float* ew1  = (const float*)d_in[1];
  const float* eb1  = (const float*)d_in[2];
  const float* ew2  = (const float*)d_in[3];
  const float* eb2  = (const float*)d_in[4];
  const float* ew3  = (const float*)d_in[5];
  const float* eb3  = (const float*)d_in[6];
  const float* qw   = (const float*)d_in[7];
  const float* qb   = (const float*)d_in[8];
  const float* cb   = (const float*)d_in[9];
  const float* pw   = (const float*)d_in[10];
  const float* pb   = (const float*)d_in[11];
  const float* dw1  = (const float*)d_in[12];
  const float* db1  = (const float*)d_in[13];
  const float* dtw2 = (const float*)d_in[14];
  const float* dtb2 = (const float*)d_in[15];
  const float* dtw3 = (const float*)d_in[16];
  const float* dtb3 = (const float*)d_in[17];

  char* wsb = (char*)d_ws;
  float*    h1p  = (float*)(wsb + OFF_A);
  _Float16* Ap   = (_Float16*)(wsb + OFF_A);
  int4*     binfo= (int4*)(wsb + OFF_BINFO);
  _Float16* d2pH = (_Float16*)(wsb + OFF_A);
  float*    h2p  = (float*)(wsb + OFF_B);
  _Float16* qH   = (_Float16*)(wsb + OFF_B);
  float*    xpad = (float*)(wsb + OFF_C);
  float*    h3   = (float*)(wsb + OFF_C);
  _Float16* d1pH = (_Float16*)(wsb + OFF_C);
  float*    zff  = (float*)(wsb + OFF_D);
  _Float16* Bp   = (_Float16*)(wsb + OFF_E);
  float*    PC   = (float*)(wsb + OFF_E);
  float*    znb  = (float*)(wsb + OFF_ZN);
  float*    cnb  = (float*)(wsb + OFF_CN);
  int*      idxb = (int*)(wsb + OFF_IDX);
  float*    accum= (float*)(wsb + OFF_ACC);
  _Float16* wh2  = (_Float16*)(wsb + OFF_WR2);
  _Float16* whd1 = (_Float16*)(wsb + OFF_WHD1);
  float*    wr3  = (float*)(wsb + OFF_WR3);
  float*    qwT  = (float*)(wsb + OFF_QWT);
  double*   wd2  = (double*)(wsb + OFF_WD2);
  double*   wd3  = (double*)(wsb + OFF_WD3);
  double*   wd1  = (double*)(wsb + OFF_WD1);

  float* out      = (float*)d_out;
  float* outLoss  = out + 786432;
  float* outIdxF  = out + 786433;

  // all prep (weight reshape/widen + encoder pad zeros) in one kernel
  hipLaunchKernelGGL(prep_k, dim3(3626), dim3(256), 0, stream,
                     dtw2, wh2, dtw3, wr3, qw, qwT, ew2, wd2, ew3, wd3,
                     ew1, wd1, dw1, whd1, xpad, h1p, h2p);

  // encoder: per-op fp32-rounded (f64-exact inside each op)
  hipLaunchKernelGGL(padx_k,    dim3(3072),  dim3(256), 0, stream, x, xpad);
  hipLaunchKernelGGL(conv1_k,   dim3(2048),  dim3(256), 0, stream, xpad, wd1, eb1, h1p);
  hipLaunchKernelGGL(conv2_k,   dim3(512),   dim3(256), 0, stream, h1p, wd2, eb2, h2p);
  hipLaunchKernelGGL(conv3_k,   dim3(512),   dim3(256), 0, stream, h2p, wd3, eb3, h3);
  hipLaunchKernelGGL(qconv_z_k, dim3(16384), dim3(256), 0, stream, h3, qwT, qb, zff, Ap, znb);

  // VQ: fp16 K=256 MFMA filter + binfo-pruned exact rescore
  hipLaunchKernelGGL(cbprep_k,    dim3(8192),  dim3(256), 0, stream, cb, Bp, cnb);
  hipLaunchKernelGGL(vq_gemm_k,   dim3(8192),  dim3(256), 0, stream, Ap, Bp, cnb, binfo);
  hipLaunchKernelGGL(vq_phase3_k, dim3(4096),  dim3(256), 0, stream, zff, cb, znb, cnb, binfo, idxb, accum);
  hipLaunchKernelGGL(commit_k,    dim3(16384), dim3(256), 0, stream, zff, cb, idxb, accum, outIdxF);

  // decoder f16-MFMA (pqconv folded through codebook: q = PC[idx] + b)
  hipLaunchKernelGGL(pc_k,          dim3(4096), dim3(256), 0, stream, cb, pw, PC);
  hipLaunchKernelGGL(padzero_dec_k, dim3(1536), dim3(256), 0, stream, qH, d1pH, d2pH);
  hipLaunchKernelGGL(gather_pc_k,   dim3(8192), dim3(256), 0, stream, PC, idxb, pb, qH);
  hipLaunchKernelGGL(dconv1_k,      dim3(2048), dim3(256), 0, stream, qH, whd1, db1, d1pH);
  hipLaunchKernelGGL(convt2_k,      dim3(8192), dim3(256), 0, stream, d1pH, wh2, dtb2, d2pH);
  hipLaunchKernelGGL(convt3_k,      dim3(1024), dim3(256), 0, stream, d2pH, wr3, dtb3, out, accum, outLoss);
}

// Round 13
// 1251.868 us; speedup vs baseline: 1.2748x; 1.2748x over previous
//
#include <hip/hip_runtime.h>

// ---------------------------------------------------------------------------
// VQ-VAE forward, round 22: r19 compute kernels (best: 1338us) + dispatch
// fusion 19 -> 11: padx into prep; cbprep(+accum zero) into qconv mega;
// commit+pc into phase3 mega (commit reuses z4 registers -> removes a full
// 33MB pass); padzero_dec into gather mega. Aliasing verified against the
// workspace lifetime graph (Bp dies after vq_gemm; binfo after phase3).
// r21 co x16 reverted (grid halving killed occupancy: 338us).
//
// d_out (float32): recon[786432] | commit_loss[1] | indices[16384]
//
// Workspace (BYTE offsets), ~86.6 MB peak:
#define OFF_A     ((size_t)0)          // h1p / Ap / d2pH(f16)
#define OFF_BINFO ((size_t)8388608)
#define OFF_B     ((size_t)34611200)   // h2p / qH(f16)
#define OFF_C     ((size_t)43532288)   // xpad / h3 / d1pH(f16)
#define OFF_D     ((size_t)52453376)   // zf
#define OFF_E     ((size_t)69230592)   // Bp / PC
#define OFF_ZN    ((size_t)81813504)
#define OFF_CN    ((size_t)81879040)
#define OFF_IDX   ((size_t)81911808)
#define OFF_ACC   ((size_t)81977344)
#define OFF_WR2   ((size_t)81977600)   // f16 convt2 weights 512KB, then whd1 f16 288KB
#define OFF_WHD1  ((size_t)82501888)   // = OFF_WR2 + 524288
#define OFF_WR3   ((size_t)83026176)
#define OFF_QWT   ((size_t)83050752)
#define OFF_WD2   ((size_t)83181824)   // f64 conv2 weights, 2 MB
#define OFF_WD3   ((size_t)85278976)   // f64 conv3 weights, 1.18 MB
#define OFF_WD1   ((size_t)86458624)   // f64 conv1 weights, 48 KB

#define VQ_MARGIN 1.2e-4f
#define LDSS 40

typedef __attribute__((ext_vector_type(8))) _Float16 f16x8;
typedef __attribute__((ext_vector_type(4))) float f32x4;

// ---------- helpers ----------
__device__ __forceinline__ unsigned fkey(float f) {
  unsigned u = __float_as_uint(f);
  return (u & 0x80000000u) ? ~u : (u | 0x80000000u);
}
__device__ __forceinline__ float funkey(unsigned k) {
  unsigned u = (k & 0x80000000u) ? (k ^ 0x80000000u) : ~k;
  return __uint_as_float(u);
}
__device__ __forceinline__ void padzero_img(float* base, int S, int t) {
  for (int e = t; e < 4 * S - 4; e += 256) {
    int rr, cc;
    if (e < S) { rr = 0; cc = e; }
    else if (e < 2 * S) { rr = S - 1; cc = e - S; }
    else { rr = ((e - 2 * S) >> 1) + 1; cc = (e & 1) ? (S - 1) : 0; }
    base[rr * S + cc] = 0.0f;
  }
}
__device__ __forceinline__ void padzero_img_h(_Float16* base, int S, int t) {
  for (int e = t; e < 4 * S - 4; e += 256) {
    int rr, cc;
    if (e < S) { rr = 0; cc = e; }
    else if (e < 2 * S) { rr = S - 1; cc = e - S; }
    else { rr = ((e - 2 * S) >> 1) + 1; cc = (e & 1) ? (S - 1) : 0; }
    base[rr * S + cc] = (_Float16)0.0f;
  }
}

// ---------- prep mega: weight reshapes/widens + enc pad zeros + padx ----------
__global__ __launch_bounds__(256) void prep_k(
    const float* __restrict__ dtw2, _Float16* __restrict__ wh2,
    const float* __restrict__ dtw3, float* __restrict__ wr3,
    const float* __restrict__ qw,   float* __restrict__ qwT,
    const float* __restrict__ ew2,  double* __restrict__ wd2,
    const float* __restrict__ ew3,  double* __restrict__ wd3,
    const float* __restrict__ ew1,  double* __restrict__ wd1,
    const float* __restrict__ dw1,  _Float16* __restrict__ whd1,
    const float* __restrict__ x,
    float* __restrict__ xpad, float* __restrict__ h1p, float* __restrict__ h2p) {
  int b = blockIdx.x, t = threadIdx.x;
  if (b < 256) {          // wresh2 -> f16 [cls][co][ci][4], k-order {d1,d0,d3,d2}
    int tid = b * 256 + t;
    int ci = tid & 127, co = (tid >> 7) & 127, cls = tid >> 14;
    int kh0 = 1 - (cls >> 1), kw0 = 1 - (cls & 1);
    const float* s = dtw2 + ((size_t)ci * 128 + co) * 16;
    _Float16* d = wh2 + (size_t)tid * 4;
    float d0 = s[kh0 * 4 + kw0];       float d1v = s[kh0 * 4 + kw0 + 2];
    float d2v = s[(kh0 + 2) * 4 + kw0]; float d3v = s[(kh0 + 2) * 4 + kw0 + 2];
    d[0] = (_Float16)d1v; d[1] = (_Float16)d0;
    d[2] = (_Float16)d3v; d[3] = (_Float16)d2v;
  } else if (b < 262) {                // wresh3
    int tid = (b - 256) * 256 + t;
    if (tid < 1536) {
      int ci = tid & 127, co = (tid >> 7) % 3, cls = tid / 384;
      int kh0 = 1 - (cls >> 1), kw0 = 1 - (cls & 1);
      const float* s = dtw3 + ((size_t)ci * 3 + co) * 16;
      float* d = wr3 + (size_t)tid * 4;
      d[0] = s[kh0 * 4 + kw0];       d[1] = s[kh0 * 4 + kw0 + 2];
      d[2] = s[(kh0 + 2) * 4 + kw0]; d[3] = s[(kh0 + 2) * 4 + kw0 + 2];
    }
  } else if (b < 390) {                // qwT
    int tid = (b - 262) * 256 + t;
    int co = tid & 255, ci = tid >> 8;
    qwT[(size_t)ci * 256 + co] = qw[(size_t)co * 128 + ci];
  } else if (b < 1414) {               // widen ew2
    int tid = (b - 390) * 256 + t;
    wd2[tid] = (double)ew2[tid];
  } else if (b < 1990) {               // widen ew3
    int tid = (b - 1414) * 256 + t;
    wd3[tid] = (double)ew3[tid];
  } else if (b < 2014) {               // widen ew1
    int tid = (b - 1990) * 256 + t;
    wd1[tid] = (double)ew1[tid];
  } else if (b < 2026) {               // pad-zero xpad (12 imgs of 258)
    padzero_img(xpad + (size_t)(b - 2014) * 66564, 258, t);
  } else if (b < 2538) {               // pad-zero h1p (512 imgs of 130)
    padzero_img(h1p + (size_t)(b - 2026) * 16900, 130, t);
  } else if (b < 3050) {               // pad-zero h2p (512 imgs of 66)
    padzero_img(h2p + (size_t)(b - 2538) * 4356, 66, t);
  } else if (b < 3626) {               // whd1: f16 [co][k], k = tap*128 + ci
    int tid = (b - 3050) * 256 + t;    // 576 blocks = 147456 exact
    int co = tid / 1152, k = tid - co * 1152;
    int tap = k >> 7, ci = k & 127;
    whd1[tid] = (_Float16)dw1[((size_t)co * 128 + ci) * 9 + tap];
  } else {                             // padx: interior copy (3072 blocks)
    int tid = (b - 3626) * 256 + t;
    int wo = tid & 255, ho = (tid >> 8) & 255, c = tid >> 16;
    xpad[((size_t)c * 258 + ho + 1) * 258 + wo + 1] = x[tid];
  }
}

// ---------- enc conv1: k=4 s=2 + ReLU, 3ci, co x8, f64 weights ----------
__global__ __launch_bounds__(256) void conv1_k(
    const float* __restrict__ xp, const double* __restrict__ wd,
    const float* __restrict__ bias, float* __restrict__ h1p) {
  int b = blockIdx.x;
  int chunk = b & 63, cog = (b >> 6) & 15, n = b >> 10;
  int t = threadIdx.x;
  int wo = t & 127, ho = chunk * 2 + (t >> 7);
  int co0 = cog * 8;
  const float* xb = xp + (size_t)n * 3 * 66564 + (size_t)(2 * ho) * 258 + 2 * wo;
  double acc[8] = {};
  for (int ci = 0; ci < 3; ++ci) {
    const float* xc = xb + (size_t)ci * 66564;
    float cf[16];
#pragma unroll
    for (int kh = 0; kh < 4; ++kh)
#pragma unroll
      for (int kw = 0; kw < 4; ++kw) cf[kh * 4 + kw] = xc[kh * 258 + kw];
    const double* wp = wd + (size_t)co0 * 48 + ci * 16;
#pragma unroll
    for (int tp = 0; tp < 16; ++tp) {
      double xd = (double)cf[tp];
#pragma unroll
      for (int cc = 0; cc < 8; ++cc)
        acc[cc] = fma(xd, wp[(size_t)cc * 48 + tp], acc[cc]);
    }
  }
#pragma unroll
  for (int cc = 0; cc < 8; ++cc) {
    float r = (float)((double)bias[co0 + cc] + acc[cc]);
    h1p[(((size_t)n * 128 + co0 + cc) * 130 + ho + 1) * 130 + wo + 1] = fmaxf(r, 0.0f);
  }
}

// ---------- enc conv2: k=4 s=2 + ReLU, co x8, float2 loads ----------
__global__ __launch_bounds__(256) void conv2_k(
    const float* __restrict__ h1p, const double* __restrict__ wd,
    const float* __restrict__ bias, float* __restrict__ h2p) {
  int b = blockIdx.x;
  int chunk = b & 15, cog = (b >> 4) & 15, n = b >> 8;
  int t = threadIdx.x;
  int wo = t & 63, ho = chunk * 4 + (t >> 6);
  int co0 = cog * 8;
  const float* xb = h1p + (size_t)n * 128 * 16900 + (size_t)(2 * ho) * 130 + 2 * wo;
  double acc[8] = {};
  for (int ci = 0; ci < 128; ++ci) {
    const float* xc = xb + (size_t)ci * 16900;
    float cf[16];
#pragma unroll
    for (int kh = 0; kh < 4; ++kh) {
      float2 p0 = *(const float2*)(xc + kh * 130);
      float2 p1 = *(const float2*)(xc + kh * 130 + 2);
      cf[kh * 4 + 0] = p0.x; cf[kh * 4 + 1] = p0.y;
      cf[kh * 4 + 2] = p1.x; cf[kh * 4 + 3] = p1.y;
    }
    const double* wp = wd + (size_t)co0 * 2048 + ci * 16;
#pragma unroll
    for (int tp = 0; tp < 16; ++tp) {
      double xd = (double)cf[tp];
#pragma unroll
      for (int cc = 0; cc < 8; ++cc)
        acc[cc] = fma(xd, wp[(size_t)cc * 2048 + tp], acc[cc]);
    }
  }
#pragma unroll
  for (int cc = 0; cc < 8; ++cc) {
    float r = (float)((double)bias[co0 + cc] + acc[cc]);
    h2p[(((size_t)n * 128 + co0 + cc) * 66 + ho + 1) * 66 + wo + 1] = fmaxf(r, 0.0f);
  }
}

// ---------- enc conv3: k=3 s=1 (no relu), co x8, f64 weights ----------
__global__ __launch_bounds__(256) void conv3_k(
    const float* __restrict__ h2p, const double* __restrict__ wd,
    const float* __restrict__ bias, float* __restrict__ h3) {
  int b = blockIdx.x;
  int chunk = b & 15, cog = (b >> 4) & 15, n = b >> 8;
  int t = threadIdx.x;
  int wo = t & 63, ho = chunk * 4 + (t >> 6);
  int co0 = cog * 8;
  const float* xb = h2p + (size_t)n * 128 * 4356 + (size_t)ho * 66 + wo;
  double acc[8] = {};
  for (int ci = 0; ci < 128; ++ci) {
    const float* xc = xb + (size_t)ci * 4356;
    float cf[9];
#pragma unroll
    for (int kh = 0; kh < 3; ++kh)
#pragma unroll
      for (int kw = 0; kw < 3; ++kw) cf[kh * 3 + kw] = xc[kh * 66 + kw];
    const double* wp = wd + (size_t)co0 * 1152 + ci * 9;
#pragma unroll
    for (int tp = 0; tp < 9; ++tp) {
      double xd = (double)cf[tp];
#pragma unroll
      for (int cc = 0; cc < 8; ++cc)
        acc[cc] = fma(xd, wp[(size_t)cc * 1152 + tp], acc[cc]);
    }
  }
#pragma unroll
  for (int cc = 0; cc < 8; ++cc)
    h3[(((size_t)n * 128 + co0 + cc) << 12) + (ho << 6) + wo] =
        (float)((double)bias[co0 + cc] + acc[cc]);
}

// ---------- qconv mega: 1x1 conv (zf+Ap+znorm) + cbprep + accum zero ----------
__global__ __launch_bounds__(256) void qconv_mega_k(
    const float* __restrict__ h3, const float* __restrict__ wT,
    const float* __restrict__ bias, float* __restrict__ zf,
    _Float16* __restrict__ Ap, float* __restrict__ znb,
    const float* __restrict__ cb, _Float16* __restrict__ Bp,
    float* __restrict__ cnb, float* __restrict__ accum) {
  __shared__ double wsum[4];
  int b = blockIdx.x;
  int t = threadIdx.x;
  if (b >= 16384) {                    // cbprep (8192 blocks)
    if (b == 16384 && t == 0) *accum = 0.0f;
    int k = b - 16384;
    float c = cb[(size_t)k * 256 + t];
    Bp[(size_t)k * 256 + t] = (_Float16)(c * 512.0f);
    float xx = c * c;
    double s = (double)xx;
#pragma unroll
    for (int off = 32; off > 0; off >>= 1) s += __shfl_down(s, off, 64);
    if ((t & 63) == 0) wsum[t >> 6] = s;
    __syncthreads();
    if (t == 0) cnb[k] = (float)((wsum[0] + wsum[1]) + (wsum[2] + wsum[3]));
    return;
  }
  int p  = b;
  int co = t;
  int n  = p >> 12;
  int hw = p & 4095;
  const float* xp = h3 + ((size_t)n * 128) * 4096 + hw;
  double a[4] = {0.0, 0.0, 0.0, 0.0};
  for (int ci = 0; ci < 128; ci += 4) {
#pragma unroll
    for (int u = 0; u < 4; ++u) {
      float xv = xp[(size_t)(ci + u) * 4096];
      a[u] = fma((double)xv, (double)wT[(size_t)(ci + u) * 256 + co], a[u]);
    }
  }
  double acc = (double)bias[co] + ((a[0] + a[1]) + (a[2] + a[3]));
  float zv = (float)acc;
  zf[(size_t)p * 256 + co] = zv;
  Ap[(size_t)p * 256 + co] = (_Float16)zv;
  float xx = zv * zv;          // elementwise square op: fp32-rounded
  double s = (double)xx;       // sum op: f64-exact, rounded once
#pragma unroll
  for (int off = 32; off > 0; off >>= 1) s += __shfl_down(s, off, 64);
  if ((co & 63) == 0) wsum[co >> 6] = s;
  __syncthreads();
  if (co == 0) znb[p] = (float)((wsum[0] + wsum[1]) + (wsum[2] + wsum[3]));
}

// ---------- VQ filter GEMM: 128x128 tile, 16x16x32 f16 MFMA, K=256 ----------
__global__ __launch_bounds__(256, 2) void vq_gemm_k(
    const _Float16* __restrict__ Ah, const _Float16* __restrict__ Bh,
    const float* __restrict__ cnArr, int4* __restrict__ binfo) {
  __shared__ __align__(16) _Float16 As[128 * LDSS];
  __shared__ __align__(16) _Float16 Bs[128 * LDSS];
  __shared__ unsigned loc[128];
  __shared__ int cnt_sh[128];
  __shared__ int cand_sh[128][2];
  const int t = threadIdx.x;
  const int w = t >> 6, L = t & 63;
  const int mb = blockIdx.x >> 6;
  const int nb = blockIdx.x & 63;
  const int m0 = mb << 7, n0 = nb << 7;
  if (t < 128) { loc[t] = 0xFFFFFFFFu; cnt_sh[t] = 0; }
  f32x4 acc[4][4] = {};
  const int wr = (w >> 1) << 6, wc = (w & 1) << 6;
  const int srow = L >> 2, kg = L & 3;
  const int q = L >> 4, ln = L & 15;
  for (int kk = 0; kk < 256; kk += 32) {
    __syncthreads();
#pragma unroll
    for (int c = 0; c < 2; ++c) {
      const int row = (w << 5) + (c << 4) + srow;
      const f16x8 av = *(const f16x8*)(Ah + (size_t)(m0 + row) * 256 + kk + kg * 8);
      *(f16x8*)(&As[row * LDSS + kg * 8]) = av;
      const f16x8 bv = *(const f16x8*)(Bh + (size_t)(n0 + row) * 256 + kk + kg * 8);
      *(f16x8*)(&Bs[row * LDSS + kg * 8]) = bv;
    }
    __syncthreads();
    f16x8 af[4], bf[4];
#pragma unroll
    for (int i = 0; i < 4; ++i)
      af[i] = *(const f16x8*)(&As[(wr + 16 * i + ln) * LDSS + q * 8]);
#pragma unroll
    for (int j = 0; j < 4; ++j)
      bf[j] = *(const f16x8*)(&Bs[(wc + 16 * j + ln) * LDSS + q * 8]);
#pragma unroll
    for (int i = 0; i < 4; ++i)
#pragma unroll
      for (int j = 0; j < 4; ++j)
        acc[i][j] = __builtin_amdgcn_mfma_f32_16x16x32_f16(af[i], bf[j], acc[i][j], 0, 0, 0);
  }
  float cnv[4];
#pragma unroll
  for (int j = 0; j < 4; ++j) cnv[j] = cnArr[n0 + wc + 16 * j + ln];
#pragma unroll
  for (int i = 0; i < 4; ++i)
#pragma unroll
    for (int r = 0; r < 4; ++r) {
      float mn = 3.4e38f;
#pragma unroll
      for (int j = 0; j < 4; ++j)
        mn = fminf(mn, fmaf(-0.00390625f, acc[i][j][r], cnv[j]));
      // min-reduce across the 16 lanes sharing this rib, then ONE atomic
#pragma unroll
      for (int s = 1; s < 16; s <<= 1)
        mn = fminf(mn, __shfl_xor(mn, s, 64));
      if (ln == 0) atomicMin(&loc[wr + 16 * i + 4 * q + r], fkey(mn));
    }
  __syncthreads();
#pragma unroll
  for (int i = 0; i < 4; ++i)
#pragma unroll
    for (int r = 0; r < 4; ++r) {
      const int rib = wr + 16 * i + 4 * q + r;
      const float thr = funkey(loc[rib]) + VQ_MARGIN;
#pragma unroll
      for (int j = 0; j < 4; ++j) {
        float s = fmaf(-0.00390625f, acc[i][j][r], cnv[j]);
        if (s <= thr) {
          int slot = atomicAdd(&cnt_sh[rib], 1);
          if (slot < 2) cand_sh[rib][slot] = n0 + wc + 16 * j + ln;
        }
      }
    }
  __syncthreads();
  if (t < 128) {
    int4 v;
    v.x = cnt_sh[t];
    v.y = cand_sh[t][0];
    v.z = cand_sh[t][1];
    v.w = (int)__float_as_uint(funkey(loc[t]));
    binfo[(size_t)(m0 + t) * 64 + nb] = v;
  }
}

// ---------- phase3 mega: binfo-pruned argmin + fused commit + pc_k ----------
__global__ __launch_bounds__(256) void p3_mega_k(
    const float* __restrict__ zf, const float* __restrict__ cb,
    const float* __restrict__ znArr, const float* __restrict__ cnArr,
    const int4* __restrict__ binfo, int* __restrict__ idxOut,
    float* __restrict__ accum, float* __restrict__ outIdxF,
    const float* __restrict__ pw, float* __restrict__ PC) {
  int b = blockIdx.x;
  if (b >= 4096) {                     // pc_k (4096 blocks)
    int tid = (b - 4096) * 256 + threadIdx.x;
    int co = tid & 127, k = tid >> 7;
    const float* c = cb + (size_t)k * 256;
    const float* w = pw + (size_t)co * 256;
    float a0 = 0.0f, a1 = 0.0f, a2 = 0.0f, a3 = 0.0f;
    for (int ci = 0; ci < 256; ci += 4) {
      a0 = fmaf(c[ci], w[ci], a0);
      a1 = fmaf(c[ci + 1], w[ci + 1], a1);
      a2 = fmaf(c[ci + 2], w[ci + 2], a2);
      a3 = fmaf(c[ci + 3], w[ci + 3], a3);
    }
    PC[tid] = (a0 + a1) + (a2 + a3);
    return;
  }
  const int lane = threadIdx.x & 63;
  const int r = b * 4 + (threadIdx.x >> 6);
  const float* zr = zf + (size_t)r * 256;
  double z4[4];
#pragma unroll
  for (int j = 0; j < 4; ++j) z4[j] = (double)zr[lane + (j << 6)];
  const float znr = znArr[r];
  int4 bi = binfo[(size_t)r * 64 + lane];
  float bv = __uint_as_float((unsigned)bi.w);
  float m = bv;
#pragma unroll
  for (int off = 32; off > 0; off >>= 1) m = fminf(m, __shfl_down(m, off, 64));
  m = __shfl(m, 0, 64);
  const float thr = m + VQ_MARGIN;
  unsigned long long mask = __ballot(bv <= thr);
  float bestd = 3.4e38f;
  int bestk = 0x7fffffff;
  while (mask) {
    const int nb = (int)__builtin_ctzll(mask);
    mask &= mask - 1;
    const int c  = __shfl(bi.x, nb, 64);
    const int k0 = __shfl(bi.y, nb, 64);
    const int k1 = __shfl(bi.z, nb, 64);
    const int nsc = (c <= 2) ? c : 128;
    for (int s2 = 0; s2 < nsc; ++s2) {
      const int k = (c <= 2) ? (s2 == 0 ? k0 : k1) : (nb * 128 + s2);
      const float* ck = cb + (size_t)k * 256;
      double p = 0.0;
#pragma unroll
      for (int j = 0; j < 4; ++j)
        p = fma(z4[j], (double)ck[lane + (j << 6)], p);
#pragma unroll
      for (int off = 32; off > 0; off >>= 1) p += __shfl_down(p, off, 64);
      if (lane == 0) {
        float mm2 = (float)(2.0 * p);
        float t1 = znr + cnArr[k];
        float d = t1 - mm2;
        if (d < bestd || (d == bestd && k < bestk)) { bestd = d; bestk = k; }
      }
    }
  }
  // fused commit: broadcast bestk, compute sum((cb[k]-zf)^2) for this row
  const int kk = __shfl(bestk, 0, 64);
  const float* ck2 = cb + (size_t)kk * 256;
  float v = 0.0f;
#pragma unroll
  for (int j = 0; j < 4; ++j) {
    float d = ck2[lane + (j << 6)] - (float)z4[j];
    v = fmaf(d, d, v);
  }
#pragma unroll
  for (int off = 32; off > 0; off >>= 1) v += __shfl_down(v, off, 64);
  if (lane == 0) {
    idxOut[r] = kk;
    outIdxF[r] = (float)kk;
    atomicAdd(accum, v);
  }
}

// ---------- gather mega: q = gather(PC, idx)+bias -> f16, + decoder pads ----------
__global__ __launch_bounds__(256) void gather_mega_k(
    const float* __restrict__ PC, const int* __restrict__ idxArr,
    const float* __restrict__ pb, _Float16* __restrict__ qH,
    _Float16* __restrict__ d1pH, _Float16* __restrict__ d2pH) {
  int b = blockIdx.x, t = threadIdx.x;
  if (b >= 8192) {                     // padzero_dec (1536 blocks)
    int bb = b - 8192;
    if (bb < 512)       padzero_img_h(qH + (size_t)bb * 4356, 66, t);
    else if (bb < 1024) padzero_img_h(d1pH + (size_t)(bb - 512) * 4356, 66, t);
    else                padzero_img_h(d2pH + (size_t)(bb - 1024) * 16900, 130, t);
    return;
  }
  int tid = b * 256 + t;
  int hw = tid & 4095;
  int co = (tid >> 12) & 127;
  int n  = tid >> 19;
  int p  = (n << 12) + hw;
  int h = hw >> 6, w2 = hw & 63;
  qH[(((size_t)n * 128 + co) * 66 + h + 1) * 66 + w2 + 1] =
      (_Float16)(PC[(size_t)idxArr[p] * 128 + co] + pb[co]);
}

// ---------- dec conv1: f16 MFMA implicit GEMM (16co x 16px, K=1152) ----------
__global__ __launch_bounds__(256) void dconv1_k(
    const _Float16* __restrict__ qH, const _Float16* __restrict__ wa,
    const float* __restrict__ bias, _Float16* __restrict__ d1pH) {
  int b = blockIdx.x;
  int ho = b & 63, cog = (b >> 6) & 7, n = b >> 9;
  int t = threadIdx.x;
  int wv = t >> 6, l = t & 63;
  int q = l >> 4, ln = l & 15;
  int wo0 = wv << 4;
  const unsigned short* qb = (const unsigned short*)qH + (size_t)n * 128 * 4356;
  const _Float16* ap = wa + (size_t)(cog * 16 + ln) * 1152 + q * 8;
  f32x4 acc = {0.0f, 0.0f, 0.0f, 0.0f};
#pragma unroll
  for (int s = 0; s < 36; ++s) {
    const int tap = s >> 2, dh = tap / 3, dw = tap % 3;
    const int cig = ((s & 3) << 5) + (q << 3);
    const unsigned short* bp =
        qb + (size_t)cig * 4356 + (ho + dh) * 66 + wo0 + ln + dw;
    unsigned v0 = bp[0],        v1 = bp[4356];
    unsigned v2 = bp[2 * 4356], v3 = bp[3 * 4356];
    unsigned v4 = bp[4 * 4356], v5 = bp[5 * 4356];
    unsigned v6 = bp[6 * 4356], v7 = bp[7 * 4356];
    union { unsigned u[4]; f16x8 h; } bb;
    bb.u[0] = v0 | (v1 << 16);
    bb.u[1] = v2 | (v3 << 16);
    bb.u[2] = v4 | (v5 << 16);
    bb.u[3] = v6 | (v7 << 16);
    const f16x8 af = *(const f16x8*)(ap + s * 32);
    acc = __builtin_amdgcn_mfma_f32_16x16x32_f16(af, bb.h, acc, 0, 0, 0);
  }
#pragma unroll
  for (int r = 0; r < 4; ++r) {
    int co = (cog << 4) + (q << 2) + r;
    d1pH[(((size_t)n * 128 + co) * 66 + ho + 1) * 66 + wo0 + ln + 1] =
        (_Float16)fmaxf(bias[co] + acc[r], 0.0f);
  }
}

// ---------- convt2: f16 MFMA implicit GEMM (16co x 16px tiles, K=512) ----------
__global__ __launch_bounds__(256) void convt2_k(
    const _Float16* __restrict__ xh, const _Float16* __restrict__ wh,
    const float* __restrict__ bias, _Float16* __restrict__ y) {
  int b = blockIdx.x;
  int i = b & 63, cog = (b >> 6) & 7, cls = (b >> 9) & 3, n = b >> 11;
  int cph = cls >> 1, cpw = cls & 1;
  int t = threadIdx.x;
  int wv = t >> 6, l = t & 63;
  int q = l >> 4, ln = l & 15;
  int wb = (wv << 4) + ln;
  int co0 = cog << 4;
  int r0 = i + 1 + cph, r1 = r0 - 1;
  int c1 = wb + cpw;
  int o0 = r0 * 66 + c1, o1 = r1 * 66 + c1;
  const unsigned short* xb =
      (const unsigned short*)xh + (size_t)n * 128 * 4356 + (size_t)(q * 2) * 4356;
  const _Float16* ap = wh + (size_t)(cls * 128 + co0 + ln) * 512 + q * 8;
  f32x4 acc = {0.0f, 0.0f, 0.0f, 0.0f};
  for (int s = 0; s < 16; ++s) {
    const unsigned short* pa = xb + (size_t)(s * 8) * 4356;
    const unsigned short* pb2 = pa + 4356;
    unsigned v0 = pa[o0], v1 = pa[o0 + 1];
    unsigned v2 = pa[o1], v3 = pa[o1 + 1];
    unsigned v4 = pb2[o0], v5 = pb2[o0 + 1];
    unsigned v6 = pb2[o1], v7 = pb2[o1 + 1];
    union { unsigned u[4]; f16x8 h; } bb;
    bb.u[0] = v0 | (v1 << 16);
    bb.u[1] = v2 | (v3 << 16);
    bb.u[2] = v4 | (v5 << 16);
    bb.u[3] = v6 | (v7 << 16);
    const f16x8 af = *(const f16x8*)(ap + s * 32);
    acc = __builtin_amdgcn_mfma_f32_16x16x32_f16(af, bb.h, acc, 0, 0, 0);
  }
  int ho = 2 * i + cph, wo = 2 * wb + cpw;
#pragma unroll
  for (int r = 0; r < 4; ++r) {
    int co = co0 + q * 4 + r;
    y[(((size_t)n * 128 + co) * 130 + ho + 1) * 130 + wo + 1] =
        (_Float16)fmaxf(bias[co] + acc[r], 0.0f);
  }
}

// ---------- convt3: parity-specialized, 3 co/thread, f16 input ----------
__global__ __launch_bounds__(256) void convt3_k(
    const _Float16* __restrict__ xh, const float* __restrict__ wr,
    const float* __restrict__ bias, float* __restrict__ y,
    const float* __restrict__ accum, float* __restrict__ outLoss) {
  int b = blockIdx.x;
  if (b == 0 && threadIdx.x == 0) *outLoss = *accum * (1.0f / 4194304.0f);
  int chunk = b & 63, cls = (b >> 6) & 3, n = b >> 8;
  int cph = cls >> 1, cpw = cls & 1;
  int t = threadIdx.x;
  int wb = t & 127, i = chunk * 2 + (t >> 7);
  int ho = 2 * i + cph, wo = 2 * wb + cpw;
  int r0 = i + 1 + cph, r1 = r0 - 1;
  int c0 = wb + 1 + cpw, c1 = c0 - 1;
  const _Float16* xb = xh + (size_t)n * 128 * 16900;
  float acc[3] = {0.0f, 0.0f, 0.0f};
  for (int ci = 0; ci < 128; ++ci) {
    const _Float16* xc = xb + (size_t)ci * 16900;
    float x00 = (float)xc[r0 * 130 + c0], x01 = (float)xc[r0 * 130 + c1];
    float x10 = (float)xc[r1 * 130 + c0], x11 = (float)xc[r1 * 130 + c1];
#pragma unroll
    for (int cc = 0; cc < 3; ++cc) {
      const float* w4 = wr + (((size_t)cls * 3 + cc) * 128 + ci) * 4;
      acc[cc] = fmaf(x00, w4[0], acc[cc]);
      acc[cc] = fmaf(x01, w4[1], acc[cc]);
      acc[cc] = fmaf(x10, w4[2], acc[cc]);
      acc[cc] = fmaf(x11, w4[3], acc[cc]);
    }
  }
#pragma unroll
  for (int cc = 0; cc < 3; ++cc)
    y[(((size_t)n * 3 + cc) << 16) + (ho << 8) + wo] = bias[cc] + acc[cc];
}

// ---------------------------------------------------------------------------
extern "C" void kernel_launch(void* const* d_in, const int* in_sizes, int n_in,
                              void* d_out, int out_size, void* d_ws, size_t ws_size,
                              hipStream_t stream) {
  const float* x    = (const float*)d_in[0];
  const float* ew1  = (const float*)d_in[1];
  const float* eb1  = (const float*)d_in[2];
  const float* ew2  = (const float*)d_in[3];
  const float* eb2  = (const float*)d_in[4];
  const float* ew3  = (const float*)d_in[5];
  const float* eb3  = (const float*)d_in[6];
  const float* qw   = (const float*)d_in[7];
  const float* qb   = (const float*)d_in[8];
  const float* cb   = (const float*)d_in[9];
  const float* pw   = (const float*)d_in[10];
  const float* pb   = (const float*)d_in[11];
  const float* dw1  = (const float*)d_in[12];
  const float* db1  = (const float*)d_in[13];
  const float* dtw2 = (const float*)d_in[14];
  const float* dtb2 = (const float*)d_in[15];
  const float* dtw3 = (const float*)d_in[16];
  const float* dtb3 = (const float*)d_in[17];

  char* wsb = (char*)d_ws;
  float*    h1p  = (float*)(wsb + OFF_A);
  _Float16* Ap   = (_Float16*)(wsb + OFF_A);
  int4*     binfo= (int4*)(wsb + OFF_BINFO);
  _Float16* d2pH = (_Float16*)(wsb + OFF_A);
  float*    h2p  = (float*)(wsb + OFF_B);
  _Float16* qH   = (_Float16*)(wsb + OFF_B);
  float*    xpad = (float*)(wsb + OFF_C);
  float*    h3   = (float*)(wsb + OFF_C);
  _Float16* d1pH = (_Float16*)(wsb + OFF_C);
  float*    zff  = (float*)(wsb + OFF_D);
  _Float16* Bp   = (_Float16*)(wsb + OFF_E);
  float*    PC   = (float*)(wsb + OFF_E);
  float*    znb  = (float*)(wsb + OFF_ZN);
  float*    cnb  = (float*)(wsb + OFF_CN);
  int*      idxb = (int*)(wsb + OFF_IDX);
  float*    accum= (float*)(wsb + OFF_ACC);
  _Float16* wh2  = (_Float16*)(wsb + OFF_WR2);
  _Float16* whd1 = (_Float16*)(wsb + OFF_WHD1);
  float*    wr3  = (float*)(wsb + OFF_WR3);
  float*    qwT  = (float*)(wsb + OFF_QWT);
  double*   wd2  = (double*)(wsb + OFF_WD2);
  double*   wd3  = (double*)(wsb + OFF_WD3);
  double*   wd1  = (double*)(wsb + OFF_WD1);

  float* out      = (float*)d_out;
  float* outLoss  = out + 786432;
  float* outIdxF  = out + 786433;

  // prep mega: weight reshapes/widens + pad zeros + padx interior copy
  hipLaunchKernelGGL(prep_k, dim3(6698), dim3(256), 0, stream,
                     dtw2, wh2, dtw3, wr3, qw, qwT, ew2, wd2, ew3, wd3,
                     ew1, wd1, dw1, whd1, x, xpad, h1p, h2p);

  // encoder: per-op fp32-rounded (f64-exact inside each op)
  hipLaunchKernelGGL(conv1_k,      dim3(4096),  dim3(256), 0, stream, xpad, wd1, eb1, h1p);
  hipLaunchKernelGGL(conv2_k,      dim3(1024),  dim3(256), 0, stream, h1p, wd2, eb2, h2p);
  hipLaunchKernelGGL(conv3_k,      dim3(1024),  dim3(256), 0, stream, h2p, wd3, eb3, h3);
  hipLaunchKernelGGL(qconv_mega_k, dim3(24576), dim3(256), 0, stream,
                     h3, qwT, qb, zff, Ap, znb, cb, Bp, cnb, accum);

  // VQ: fp16 K=256 MFMA filter + binfo-pruned exact rescore (+commit, +pc)
  hipLaunchKernelGGL(vq_gemm_k, dim3(8192), dim3(256), 0, stream, Ap, Bp, cnb, binfo);
  hipLaunchKernelGGL(p3_mega_k, dim3(8192), dim3(256), 0, stream,
                     zff, cb, znb, cnb, binfo, idxb, accum, outIdxF, pw, PC);

  // decoder f16-MFMA (pqconv folded through codebook: q = PC[idx] + b)
  hipLaunchKernelGGL(gather_mega_k, dim3(9728), dim3(256), 0, stream,
                     PC, idxb, pb, qH, d1pH, d2pH);
  hipLaunchKernelGGL(dconv1_k, dim3(2048), dim3(256), 0, stream, qH, whd1, db1, d1pH);
  hipLaunchKernelGGL(convt2_k, dim3(8192), dim3(256), 0, stream, d1pH, wh2, dtb2, d2pH);
  hipLaunchKernelGGL(convt3_k, dim3(1024), dim3(256), 0, stream, d2pH, wr3, dtb3,
                     out, accum, outLoss);
}

// Round 14
// 1247.159 us; speedup vs baseline: 1.2797x; 1.0038x over previous
//
#include <hip/hip_runtime.h>

// ---------------------------------------------------------------------------
// VQ-VAE forward, round 23: r22 (1252us) + phase3 rescore restructured for
// ILP: dense (c>2) blocks rescored in batches of 8 (independent shfl trees
// pipeline in the LDS pipe), sparse (c<=2) candidates queued in LDS and
// flushed in batches of 8. Per-candidate f64 partial order + shfl tree
// byte-identical; final (bestd,bestk) is a lexicographic min => order-free.
// All other kernels = r22.
//
// d_out (float32): recon[786432] | commit_loss[1] | indices[16384]
//
// Workspace (BYTE offsets), ~86.6 MB peak:
#define OFF_A     ((size_t)0)          // h1p / Ap / d2pH(f16)
#define OFF_BINFO ((size_t)8388608)
#define OFF_B     ((size_t)34611200)   // h2p / qH(f16)
#define OFF_C     ((size_t)43532288)   // xpad / h3 / d1pH(f16)
#define OFF_D     ((size_t)52453376)   // zf
#define OFF_E     ((size_t)69230592)   // Bp / PC
#define OFF_ZN    ((size_t)81813504)
#define OFF_CN    ((size_t)81879040)
#define OFF_IDX   ((size_t)81911808)
#define OFF_ACC   ((size_t)81977344)
#define OFF_WR2   ((size_t)81977600)   // f16 convt2 weights 512KB, then whd1 f16 288KB
#define OFF_WHD1  ((size_t)82501888)   // = OFF_WR2 + 524288
#define OFF_WR3   ((size_t)83026176)
#define OFF_QWT   ((size_t)83050752)
#define OFF_WD2   ((size_t)83181824)   // f64 conv2 weights, 2 MB
#define OFF_WD3   ((size_t)85278976)   // f64 conv3 weights, 1.18 MB
#define OFF_WD1   ((size_t)86458624)   // f64 conv1 weights, 48 KB

#define VQ_MARGIN 1.2e-4f
#define LDSS 40

typedef __attribute__((ext_vector_type(8))) _Float16 f16x8;
typedef __attribute__((ext_vector_type(4))) float f32x4;

// ---------- helpers ----------
__device__ __forceinline__ unsigned fkey(float f) {
  unsigned u = __float_as_uint(f);
  return (u & 0x80000000u) ? ~u : (u | 0x80000000u);
}
__device__ __forceinline__ float funkey(unsigned k) {
  unsigned u = (k & 0x80000000u) ? (k ^ 0x80000000u) : ~k;
  return __uint_as_float(u);
}
__device__ __forceinline__ void padzero_img(float* base, int S, int t) {
  for (int e = t; e < 4 * S - 4; e += 256) {
    int rr, cc;
    if (e < S) { rr = 0; cc = e; }
    else if (e < 2 * S) { rr = S - 1; cc = e - S; }
    else { rr = ((e - 2 * S) >> 1) + 1; cc = (e & 1) ? (S - 1) : 0; }
    base[rr * S + cc] = 0.0f;
  }
}
__device__ __forceinline__ void padzero_img_h(_Float16* base, int S, int t) {
  for (int e = t; e < 4 * S - 4; e += 256) {
    int rr, cc;
    if (e < S) { rr = 0; cc = e; }
    else if (e < 2 * S) { rr = S - 1; cc = e - S; }
    else { rr = ((e - 2 * S) >> 1) + 1; cc = (e & 1) ? (S - 1) : 0; }
    base[rr * S + cc] = (_Float16)0.0f;
  }
}

// ---------- prep mega: weight reshapes/widens + enc pad zeros + padx ----------
__global__ __launch_bounds__(256) void prep_k(
    const float* __restrict__ dtw2, _Float16* __restrict__ wh2,
    const float* __restrict__ dtw3, float* __restrict__ wr3,
    const float* __restrict__ qw,   float* __restrict__ qwT,
    const float* __restrict__ ew2,  double* __restrict__ wd2,
    const float* __restrict__ ew3,  double* __restrict__ wd3,
    const float* __restrict__ ew1,  double* __restrict__ wd1,
    const float* __restrict__ dw1,  _Float16* __restrict__ whd1,
    const float* __restrict__ x,
    float* __restrict__ xpad, float* __restrict__ h1p, float* __restrict__ h2p) {
  int b = blockIdx.x, t = threadIdx.x;
  if (b < 256) {          // wresh2 -> f16 [cls][co][ci][4], k-order {d1,d0,d3,d2}
    int tid = b * 256 + t;
    int ci = tid & 127, co = (tid >> 7) & 127, cls = tid >> 14;
    int kh0 = 1 - (cls >> 1), kw0 = 1 - (cls & 1);
    const float* s = dtw2 + ((size_t)ci * 128 + co) * 16;
    _Float16* d = wh2 + (size_t)tid * 4;
    float d0 = s[kh0 * 4 + kw0];       float d1v = s[kh0 * 4 + kw0 + 2];
    float d2v = s[(kh0 + 2) * 4 + kw0]; float d3v = s[(kh0 + 2) * 4 + kw0 + 2];
    d[0] = (_Float16)d1v; d[1] = (_Float16)d0;
    d[2] = (_Float16)d3v; d[3] = (_Float16)d2v;
  } else if (b < 262) {                // wresh3
    int tid = (b - 256) * 256 + t;
    if (tid < 1536) {
      int ci = tid & 127, co = (tid >> 7) % 3, cls = tid / 384;
      int kh0 = 1 - (cls >> 1), kw0 = 1 - (cls & 1);
      const float* s = dtw3 + ((size_t)ci * 3 + co) * 16;
      float* d = wr3 + (size_t)tid * 4;
      d[0] = s[kh0 * 4 + kw0];       d[1] = s[kh0 * 4 + kw0 + 2];
      d[2] = s[(kh0 + 2) * 4 + kw0]; d[3] = s[(kh0 + 2) * 4 + kw0 + 2];
    }
  } else if (b < 390) {                // qwT
    int tid = (b - 262) * 256 + t;
    int co = tid & 255, ci = tid >> 8;
    qwT[(size_t)ci * 256 + co] = qw[(size_t)co * 128 + ci];
  } else if (b < 1414) {               // widen ew2
    int tid = (b - 390) * 256 + t;
    wd2[tid] = (double)ew2[tid];
  } else if (b < 1990) {               // widen ew3
    int tid = (b - 1414) * 256 + t;
    wd3[tid] = (double)ew3[tid];
  } else if (b < 2014) {               // widen ew1
    int tid = (b - 1990) * 256 + t;
    wd1[tid] = (double)ew1[tid];
  } else if (b < 2026) {               // pad-zero xpad (12 imgs of 258)
    padzero_img(xpad + (size_t)(b - 2014) * 66564, 258, t);
  } else if (b < 2538) {               // pad-zero h1p (512 imgs of 130)
    padzero_img(h1p + (size_t)(b - 2026) * 16900, 130, t);
  } else if (b < 3050) {               // pad-zero h2p (512 imgs of 66)
    padzero_img(h2p + (size_t)(b - 2538) * 4356, 66, t);
  } else if (b < 3626) {               // whd1: f16 [co][k], k = tap*128 + ci
    int tid = (b - 3050) * 256 + t;    // 576 blocks = 147456 exact
    int co = tid / 1152, k = tid - co * 1152;
    int tap = k >> 7, ci = k & 127;
    whd1[tid] = (_Float16)dw1[((size_t)co * 128 + ci) * 9 + tap];
  } else {                             // padx: interior copy (3072 blocks)
    int tid = (b - 3626) * 256 + t;
    int wo = tid & 255, ho = (tid >> 8) & 255, c = tid >> 16;
    xpad[((size_t)c * 258 + ho + 1) * 258 + wo + 1] = x[tid];
  }
}

// ---------- enc conv1: k=4 s=2 + ReLU, 3ci, co x8, f64 weights ----------
__global__ __launch_bounds__(256) void conv1_k(
    const float* __restrict__ xp, const double* __restrict__ wd,
    const float* __restrict__ bias, float* __restrict__ h1p) {
  int b = blockIdx.x;
  int chunk = b & 63, cog = (b >> 6) & 15, n = b >> 10;
  int t = threadIdx.x;
  int wo = t & 127, ho = chunk * 2 + (t >> 7);
  int co0 = cog * 8;
  const float* xb = xp + (size_t)n * 3 * 66564 + (size_t)(2 * ho) * 258 + 2 * wo;
  double acc[8] = {};
  for (int ci = 0; ci < 3; ++ci) {
    const float* xc = xb + (size_t)ci * 66564;
    float cf[16];
#pragma unroll
    for (int kh = 0; kh < 4; ++kh)
#pragma unroll
      for (int kw = 0; kw < 4; ++kw) cf[kh * 4 + kw] = xc[kh * 258 + kw];
    const double* wp = wd + (size_t)co0 * 48 + ci * 16;
#pragma unroll
    for (int tp = 0; tp < 16; ++tp) {
      double xd = (double)cf[tp];
#pragma unroll
      for (int cc = 0; cc < 8; ++cc)
        acc[cc] = fma(xd, wp[(size_t)cc * 48 + tp], acc[cc]);
    }
  }
#pragma unroll
  for (int cc = 0; cc < 8; ++cc) {
    float r = (float)((double)bias[co0 + cc] + acc[cc]);
    h1p[(((size_t)n * 128 + co0 + cc) * 130 + ho + 1) * 130 + wo + 1] = fmaxf(r, 0.0f);
  }
}

// ---------- enc conv2: k=4 s=2 + ReLU, co x8, float2 loads ----------
__global__ __launch_bounds__(256) void conv2_k(
    const float* __restrict__ h1p, const double* __restrict__ wd,
    const float* __restrict__ bias, float* __restrict__ h2p) {
  int b = blockIdx.x;
  int chunk = b & 15, cog = (b >> 4) & 15, n = b >> 8;
  int t = threadIdx.x;
  int wo = t & 63, ho = chunk * 4 + (t >> 6);
  int co0 = cog * 8;
  const float* xb = h1p + (size_t)n * 128 * 16900 + (size_t)(2 * ho) * 130 + 2 * wo;
  double acc[8] = {};
  for (int ci = 0; ci < 128; ++ci) {
    const float* xc = xb + (size_t)ci * 16900;
    float cf[16];
#pragma unroll
    for (int kh = 0; kh < 4; ++kh) {
      float2 p0 = *(const float2*)(xc + kh * 130);
      float2 p1 = *(const float2*)(xc + kh * 130 + 2);
      cf[kh * 4 + 0] = p0.x; cf[kh * 4 + 1] = p0.y;
      cf[kh * 4 + 2] = p1.x; cf[kh * 4 + 3] = p1.y;
    }
    const double* wp = wd + (size_t)co0 * 2048 + ci * 16;
#pragma unroll
    for (int tp = 0; tp < 16; ++tp) {
      double xd = (double)cf[tp];
#pragma unroll
      for (int cc = 0; cc < 8; ++cc)
        acc[cc] = fma(xd, wp[(size_t)cc * 2048 + tp], acc[cc]);
    }
  }
#pragma unroll
  for (int cc = 0; cc < 8; ++cc) {
    float r = (float)((double)bias[co0 + cc] + acc[cc]);
    h2p[(((size_t)n * 128 + co0 + cc) * 66 + ho + 1) * 66 + wo + 1] = fmaxf(r, 0.0f);
  }
}

// ---------- enc conv3: k=3 s=1 (no relu), co x8, f64 weights ----------
__global__ __launch_bounds__(256) void conv3_k(
    const float* __restrict__ h2p, const double* __restrict__ wd,
    const float* __restrict__ bias, float* __restrict__ h3) {
  int b = blockIdx.x;
  int chunk = b & 15, cog = (b >> 4) & 15, n = b >> 8;
  int t = threadIdx.x;
  int wo = t & 63, ho = chunk * 4 + (t >> 6);
  int co0 = cog * 8;
  const float* xb = h2p + (size_t)n * 128 * 4356 + (size_t)ho * 66 + wo;
  double acc[8] = {};
  for (int ci = 0; ci < 128; ++ci) {
    const float* xc = xb + (size_t)ci * 4356;
    float cf[9];
#pragma unroll
    for (int kh = 0; kh < 3; ++kh)
#pragma unroll
      for (int kw = 0; kw < 3; ++kw) cf[kh * 3 + kw] = xc[kh * 66 + kw];
    const double* wp = wd + (size_t)co0 * 1152 + ci * 9;
#pragma unroll
    for (int tp = 0; tp < 9; ++tp) {
      double xd = (double)cf[tp];
#pragma unroll
      for (int cc = 0; cc < 8; ++cc)
        acc[cc] = fma(xd, wp[(size_t)cc * 1152 + tp], acc[cc]);
    }
  }
#pragma unroll
  for (int cc = 0; cc < 8; ++cc)
    h3[(((size_t)n * 128 + co0 + cc) << 12) + (ho << 6) + wo] =
        (float)((double)bias[co0 + cc] + acc[cc]);
}

// ---------- qconv mega: 1x1 conv (zf+Ap+znorm) + cbprep + accum zero ----------
__global__ __launch_bounds__(256) void qconv_mega_k(
    const float* __restrict__ h3, const float* __restrict__ wT,
    const float* __restrict__ bias, float* __restrict__ zf,
    _Float16* __restrict__ Ap, float* __restrict__ znb,
    const float* __restrict__ cb, _Float16* __restrict__ Bp,
    float* __restrict__ cnb, float* __restrict__ accum) {
  __shared__ double wsum[4];
  int b = blockIdx.x;
  int t = threadIdx.x;
  if (b >= 16384) {                    // cbprep (8192 blocks)
    if (b == 16384 && t == 0) *accum = 0.0f;
    int k = b - 16384;
    float c = cb[(size_t)k * 256 + t];
    Bp[(size_t)k * 256 + t] = (_Float16)(c * 512.0f);
    float xx = c * c;
    double s = (double)xx;
#pragma unroll
    for (int off = 32; off > 0; off >>= 1) s += __shfl_down(s, off, 64);
    if ((t & 63) == 0) wsum[t >> 6] = s;
    __syncthreads();
    if (t == 0) cnb[k] = (float)((wsum[0] + wsum[1]) + (wsum[2] + wsum[3]));
    return;
  }
  int p  = b;
  int co = t;
  int n  = p >> 12;
  int hw = p & 4095;
  const float* xp = h3 + ((size_t)n * 128) * 4096 + hw;
  double a[4] = {0.0, 0.0, 0.0, 0.0};
  for (int ci = 0; ci < 128; ci += 4) {
#pragma unroll
    for (int u = 0; u < 4; ++u) {
      float xv = xp[(size_t)(ci + u) * 4096];
      a[u] = fma((double)xv, (double)wT[(size_t)(ci + u) * 256 + co], a[u]);
    }
  }
  double acc = (double)bias[co] + ((a[0] + a[1]) + (a[2] + a[3]));
  float zv = (float)acc;
  zf[(size_t)p * 256 + co] = zv;
  Ap[(size_t)p * 256 + co] = (_Float16)zv;
  float xx = zv * zv;          // elementwise square op: fp32-rounded
  double s = (double)xx;       // sum op: f64-exact, rounded once
#pragma unroll
  for (int off = 32; off > 0; off >>= 1) s += __shfl_down(s, off, 64);
  if ((co & 63) == 0) wsum[co >> 6] = s;
  __syncthreads();
  if (co == 0) znb[p] = (float)((wsum[0] + wsum[1]) + (wsum[2] + wsum[3]));
}

// ---------- VQ filter GEMM: 128x128 tile, 16x16x32 f16 MFMA, K=256 ----------
__global__ __launch_bounds__(256, 2) void vq_gemm_k(
    const _Float16* __restrict__ Ah, const _Float16* __restrict__ Bh,
    const float* __restrict__ cnArr, int4* __restrict__ binfo) {
  __shared__ __align__(16) _Float16 As[128 * LDSS];
  __shared__ __align__(16) _Float16 Bs[128 * LDSS];
  __shared__ unsigned loc[128];
  __shared__ int cnt_sh[128];
  __shared__ int cand_sh[128][2];
  const int t = threadIdx.x;
  const int w = t >> 6, L = t & 63;
  const int mb = blockIdx.x >> 6;
  const int nb = blockIdx.x & 63;
  const int m0 = mb << 7, n0 = nb << 7;
  if (t < 128) { loc[t] = 0xFFFFFFFFu; cnt_sh[t] = 0; }
  f32x4 acc[4][4] = {};
  const int wr = (w >> 1) << 6, wc = (w & 1) << 6;
  const int srow = L >> 2, kg = L & 3;
  const int q = L >> 4, ln = L & 15;
  for (int kk = 0; kk < 256; kk += 32) {
    __syncthreads();
#pragma unroll
    for (int c = 0; c < 2; ++c) {
      const int row = (w << 5) + (c << 4) + srow;
      const f16x8 av = *(const f16x8*)(Ah + (size_t)(m0 + row) * 256 + kk + kg * 8);
      *(f16x8*)(&As[row * LDSS + kg * 8]) = av;
      const f16x8 bv = *(const f16x8*)(Bh + (size_t)(n0 + row) * 256 + kk + kg * 8);
      *(f16x8*)(&Bs[row * LDSS + kg * 8]) = bv;
    }
    __syncthreads();
    f16x8 af[4], bf[4];
#pragma unroll
    for (int i = 0; i < 4; ++i)
      af[i] = *(const f16x8*)(&As[(wr + 16 * i + ln) * LDSS + q * 8]);
#pragma unroll
    for (int j = 0; j < 4; ++j)
      bf[j] = *(const f16x8*)(&Bs[(wc + 16 * j + ln) * LDSS + q * 8]);
#pragma unroll
    for (int i = 0; i < 4; ++i)
#pragma unroll
      for (int j = 0; j < 4; ++j)
        acc[i][j] = __builtin_amdgcn_mfma_f32_16x16x32_f16(af[i], bf[j], acc[i][j], 0, 0, 0);
  }
  float cnv[4];
#pragma unroll
  for (int j = 0; j < 4; ++j) cnv[j] = cnArr[n0 + wc + 16 * j + ln];
#pragma unroll
  for (int i = 0; i < 4; ++i)
#pragma unroll
    for (int r = 0; r < 4; ++r) {
      float mn = 3.4e38f;
#pragma unroll
      for (int j = 0; j < 4; ++j)
        mn = fminf(mn, fmaf(-0.00390625f, acc[i][j][r], cnv[j]));
      // min-reduce across the 16 lanes sharing this rib, then ONE atomic
#pragma unroll
      for (int s = 1; s < 16; s <<= 1)
        mn = fminf(mn, __shfl_xor(mn, s, 64));
      if (ln == 0) atomicMin(&loc[wr + 16 * i + 4 * q + r], fkey(mn));
    }
  __syncthreads();
#pragma unroll
  for (int i = 0; i < 4; ++i)
#pragma unroll
    for (int r = 0; r < 4; ++r) {
      const int rib = wr + 16 * i + 4 * q + r;
      const float thr = funkey(loc[rib]) + VQ_MARGIN;
#pragma unroll
      for (int j = 0; j < 4; ++j) {
        float s = fmaf(-0.00390625f, acc[i][j][r], cnv[j]);
        if (s <= thr) {
          int slot = atomicAdd(&cnt_sh[rib], 1);
          if (slot < 2) cand_sh[rib][slot] = n0 + wc + 16 * j + ln;
        }
      }
    }
  __syncthreads();
  if (t < 128) {
    int4 v;
    v.x = cnt_sh[t];
    v.y = cand_sh[t][0];
    v.z = cand_sh[t][1];
    v.w = (int)__float_as_uint(funkey(loc[t]));
    binfo[(size_t)(m0 + t) * 64 + nb] = v;
  }
}

// ---------- phase3 mega: ILP-batched argmin + fused commit + pc_k ----------
__global__ __launch_bounds__(256) void p3_mega_k(
    const float* __restrict__ zf, const float* __restrict__ cb,
    const float* __restrict__ znArr, const float* __restrict__ cnArr,
    const int4* __restrict__ binfo, int* __restrict__ idxOut,
    float* __restrict__ accum, float* __restrict__ outIdxF,
    const float* __restrict__ pw, float* __restrict__ PC) {
  __shared__ int sq[4][128];
  int b = blockIdx.x;
  if (b >= 4096) {                     // pc_k (4096 blocks)
    int tid = (b - 4096) * 256 + threadIdx.x;
    int co = tid & 127, k = tid >> 7;
    const float* c = cb + (size_t)k * 256;
    const float* w = pw + (size_t)co * 256;
    float a0 = 0.0f, a1 = 0.0f, a2 = 0.0f, a3 = 0.0f;
    for (int ci = 0; ci < 256; ci += 4) {
      a0 = fmaf(c[ci], w[ci], a0);
      a1 = fmaf(c[ci + 1], w[ci + 1], a1);
      a2 = fmaf(c[ci + 2], w[ci + 2], a2);
      a3 = fmaf(c[ci + 3], w[ci + 3], a3);
    }
    PC[tid] = (a0 + a1) + (a2 + a3);
    return;
  }
  const int lane = threadIdx.x & 63;
  const int wid = threadIdx.x >> 6;
  const int r = b * 4 + wid;
  const float* zr = zf + (size_t)r * 256;
  double z4[4];
#pragma unroll
  for (int j = 0; j < 4; ++j) z4[j] = (double)zr[lane + (j << 6)];
  const float znr = znArr[r];
  int4 bi = binfo[(size_t)r * 64 + lane];
  float bv = __uint_as_float((unsigned)bi.w);
  float m = bv;
#pragma unroll
  for (int off = 32; off > 0; off >>= 1) m = fminf(m, __shfl_down(m, off, 64));
  m = __shfl(m, 0, 64);
  const float thr = m + VQ_MARGIN;
  unsigned long long mask = __ballot(bv <= thr);
  float bestd = 3.4e38f;
  int bestk = 0x7fffffff;
  int qn = 0;
  // walk passing blocks: sparse (c<=2) queued; dense (c>2) rescored batched-8
  while (mask) {
    const int nb = (int)__builtin_ctzll(mask);
    mask &= mask - 1;
    const int c  = __shfl(bi.x, nb, 64);
    if (c <= 2) {
      const int k0 = __shfl(bi.y, nb, 64);
      const int k1 = __shfl(bi.z, nb, 64);
      if (c >= 1) { if (lane == 0) sq[wid][qn] = k0; qn++; }
      if (c >= 2) { if (lane == 0) sq[wid][qn] = k1; qn++; }
    } else {
      const int kb = nb * 128;
      for (int s2 = 0; s2 < 128; s2 += 8) {
        double p[8];
#pragma unroll
        for (int u = 0; u < 8; ++u) {
          const float* ck = cb + (size_t)(kb + s2 + u) * 256;
          double pp = 0.0;
#pragma unroll
          for (int j = 0; j < 4; ++j)
            pp = fma(z4[j], (double)ck[lane + (j << 6)], pp);
          p[u] = pp;
        }
#pragma unroll
        for (int off = 32; off > 0; off >>= 1) {
#pragma unroll
          for (int u = 0; u < 8; ++u) p[u] += __shfl_down(p[u], off, 64);
        }
        if (lane == 0) {
#pragma unroll
          for (int u = 0; u < 8; ++u) {
            const int k = kb + s2 + u;
            float mm2 = (float)(2.0 * p[u]);
            float t1 = znr + cnArr[k];
            float d = t1 - mm2;
            if (d < bestd || (d == bestd && k < bestk)) { bestd = d; bestk = k; }
          }
        }
      }
    }
  }
  // flush sparse queue in batches of 8 (pad by repeating last k: dupes
  // cannot change a lexicographic min)
  for (int s0 = 0; s0 < qn; s0 += 8) {
    int kk8[8];
    double p[8];
#pragma unroll
    for (int u = 0; u < 8; ++u) {
      int qi = s0 + u;
      kk8[u] = sq[wid][qi < qn ? qi : (qn - 1)];
      const float* ck = cb + (size_t)kk8[u] * 256;
      double pp = 0.0;
#pragma unroll
      for (int j = 0; j < 4; ++j)
        pp = fma(z4[j], (double)ck[lane + (j << 6)], pp);
      p[u] = pp;
    }
#pragma unroll
    for (int off = 32; off > 0; off >>= 1) {
#pragma unroll
      for (int u = 0; u < 8; ++u) p[u] += __shfl_down(p[u], off, 64);
    }
    if (lane == 0) {
#pragma unroll
      for (int u = 0; u < 8; ++u) {
        const int k = kk8[u];
        float mm2 = (float)(2.0 * p[u]);
        float t1 = znr + cnArr[k];
        float d = t1 - mm2;
        if (d < bestd || (d == bestd && k < bestk)) { bestd = d; bestk = k; }
      }
    }
  }
  // fused commit: broadcast bestk, compute sum((cb[k]-zf)^2) for this row
  const int kk = __shfl(bestk, 0, 64);
  const float* ck2 = cb + (size_t)kk * 256;
  float v = 0.0f;
#pragma unroll
  for (int j = 0; j < 4; ++j) {
    float d = ck2[lane + (j << 6)] - (float)z4[j];
    v = fmaf(d, d, v);
  }
#pragma unroll
  for (int off = 32; off > 0; off >>= 1) v += __shfl_down(v, off, 64);
  if (lane == 0) {
    idxOut[r] = kk;
    outIdxF[r] = (float)kk;
    atomicAdd(accum, v);
  }
}

// ---------- gather mega: q = gather(PC, idx)+bias -> f16, + decoder pads ----------
__global__ __launch_bounds__(256) void gather_mega_k(
    const float* __restrict__ PC, const int* __restrict__ idxArr,
    const float* __restrict__ pb, _Float16* __restrict__ qH,
    _Float16* __restrict__ d1pH, _Float16* __restrict__ d2pH) {
  int b = blockIdx.x, t = threadIdx.x;
  if (b >= 8192) {                     // padzero_dec (1536 blocks)
    int bb = b - 8192;
    if (bb < 512)       padzero_img_h(qH + (size_t)bb * 4356, 66, t);
    else if (bb < 1024) padzero_img_h(d1pH + (size_t)(bb - 512) * 4356, 66, t);
    else                padzero_img_h(d2pH + (size_t)(bb - 1024) * 16900, 130, t);
    return;
  }
  int tid = b * 256 + t;
  int hw = tid & 4095;
  int co = (tid >> 12) & 127;
  int n  = tid >> 19;
  int p  = (n << 12) + hw;
  int h = hw >> 6, w2 = hw & 63;
  qH[(((size_t)n * 128 + co) * 66 + h + 1) * 66 + w2 + 1] =
      (_Float16)(PC[(size_t)idxArr[p] * 128 + co] + pb[co]);
}

// ---------- dec conv1: f16 MFMA implicit GEMM (16co x 16px, K=1152) ----------
__global__ __launch_bounds__(256) void dconv1_k(
    const _Float16* __restrict__ qH, const _Float16* __restrict__ wa,
    const float* __restrict__ bias, _Float16* __restrict__ d1pH) {
  int b = blockIdx.x;
  int ho = b & 63, cog = (b >> 6) & 7, n = b >> 9;
  int t = threadIdx.x;
  int wv = t >> 6, l = t & 63;
  int q = l >> 4, ln = l & 15;
  int wo0 = wv << 4;
  const unsigned short* qb = (const unsigned short*)qH + (size_t)n * 128 * 4356;
  const _Float16* ap = wa + (size_t)(cog * 16 + ln) * 1152 + q * 8;
  f32x4 acc = {0.0f, 0.0f, 0.0f, 0.0f};
#pragma unroll
  for (int s = 0; s < 36; ++s) {
    const int tap = s >> 2, dh = tap / 3, dw = tap % 3;
    const int cig = ((s & 3) << 5) + (q << 3);
    const unsigned short* bp =
        qb + (size_t)cig * 4356 + (ho + dh) * 66 + wo0 + ln + dw;
    unsigned v0 = bp[0],        v1 = bp[4356];
    unsigned v2 = bp[2 * 4356], v3 = bp[3 * 4356];
    unsigned v4 = bp[4 * 4356], v5 = bp[5 * 4356];
    unsigned v6 = bp[6 * 4356], v7 = bp[7 * 4356];
    union { unsigned u[4]; f16x8 h; } bb;
    bb.u[0] = v0 | (v1 << 16);
    bb.u[1] = v2 | (v3 << 16);
    bb.u[2] = v4 | (v5 << 16);
    bb.u[3] = v6 | (v7 << 16);
    const f16x8 af = *(const f16x8*)(ap + s * 32);
    acc = __builtin_amdgcn_mfma_f32_16x16x32_f16(af, bb.h, acc, 0, 0, 0);
  }
#pragma unroll
  for (int r = 0; r < 4; ++r) {
    int co = (cog << 4) + (q << 2) + r;
    d1pH[(((size_t)n * 128 + co) * 66 + ho + 1) * 66 + wo0 + ln + 1] =
        (_Float16)fmaxf(bias[co] + acc[r], 0.0f);
  }
}

// ---------- convt2: f16 MFMA implicit GEMM (16co x 16px tiles, K=512) ----------
__global__ __launch_bounds__(256) void convt2_k(
    const _Float16* __restrict__ xh, const _Float16* __restrict__ wh,
    const float* __restrict__ bias, _Float16* __restrict__ y) {
  int b = blockIdx.x;
  int i = b & 63, cog = (b >> 6) & 7, cls = (b >> 9) & 3, n = b >> 11;
  int cph = cls >> 1, cpw = cls & 1;
  int t = threadIdx.x;
  int wv = t >> 6, l = t & 63;
  int q = l >> 4, ln = l & 15;
  int wb = (wv << 4) + ln;
  int co0 = cog << 4;
  int r0 = i + 1 + cph, r1 = r0 - 1;
  int c1 = wb + cpw;
  int o0 = r0 * 66 + c1, o1 = r1 * 66 + c1;
  const unsigned short* xb =
      (const unsigned short*)xh + (size_t)n * 128 * 4356 + (size_t)(q * 2) * 4356;
  const _Float16* ap = wh + (size_t)(cls * 128 + co0 + ln) * 512 + q * 8;
  f32x4 acc = {0.0f, 0.0f, 0.0f, 0.0f};
  for (int s = 0; s < 16; ++s) {
    const unsigned short* pa = xb + (size_t)(s * 8) * 4356;
    const unsigned short* pb2 = pa + 4356;
    unsigned v0 = pa[o0], v1 = pa[o0 + 1];
    unsigned v2 = pa[o1], v3 = pa[o1 + 1];
    unsigned v4 = pb2[o0], v5 = pb2[o0 + 1];
    unsigned v6 = pb2[o1], v7 = pb2[o1 + 1];
    union { unsigned u[4]; f16x8 h; } bb;
    bb.u[0] = v0 | (v1 << 16);
    bb.u[1] = v2 | (v3 << 16);
    bb.u[2] = v4 | (v5 << 16);
    bb.u[3] = v6 | (v7 << 16);
    const f16x8 af = *(const f16x8*)(ap + s * 32);
    acc = __builtin_amdgcn_mfma_f32_16x16x32_f16(af, bb.h, acc, 0, 0, 0);
  }
  int ho = 2 * i + cph, wo = 2 * wb + cpw;
#pragma unroll
  for (int r = 0; r < 4; ++r) {
    int co = co0 + q * 4 + r;
    y[(((size_t)n * 128 + co) * 130 + ho + 1) * 130 + wo + 1] =
        (_Float16)fmaxf(bias[co] + acc[r], 0.0f);
  }
}

// ---------- convt3: parity-specialized, 3 co/thread, f16 input ----------
__global__ __launch_bounds__(256) void convt3_k(
    const _Float16* __restrict__ xh, const float* __restrict__ wr,
    const float* __restrict__ bias, float* __restrict__ y,
    const float* __restrict__ accum, float* __restrict__ outLoss) {
  int b = blockIdx.x;
  if (b == 0 && threadIdx.x == 0) *outLoss = *accum * (1.0f / 4194304.0f);
  int chunk = b & 63, cls = (b >> 6) & 3, n = b >> 8;
  int cph = cls >> 1, cpw = cls & 1;
  int t = threadIdx.x;
  int wb = t & 127, i = chunk * 2 + (t >> 7);
  int ho = 2 * i + cph, wo = 2 * wb + cpw;
  int r0 = i + 1 + cph, r1 = r0 - 1;
  int c0 = wb + 1 + cpw, c1 = c0 - 1;
  const _Float16* xb = xh + (size_t)n * 128 * 16900;
  float acc[3] = {0.0f, 0.0f, 0.0f};
  for (int ci = 0; ci < 128; ++ci) {
    const _Float16* xc = xb + (size_t)ci * 16900;
    float x00 = (float)xc[r0 * 130 + c0], x01 = (float)xc[r0 * 130 + c1];
    float x10 = (float)xc[r1 * 130 + c0], x11 = (float)xc[r1 * 130 + c1];
#pragma unroll
    for (int cc = 0; cc < 3; ++cc) {
      const float* w4 = wr + (((size_t)cls * 3 + cc) * 128 + ci) * 4;
      acc[cc] = fmaf(x00, w4[0], acc[cc]);
      acc[cc] = fmaf(x01, w4[1], acc[cc]);
      acc[cc] = fmaf(x10, w4[2], acc[cc]);
      acc[cc] = fmaf(x11, w4[3], acc[cc]);
    }
  }
#pragma unroll
  for (int cc = 0; cc < 3; ++cc)
    y[(((size_t)n * 3 + cc) << 16) + (ho << 8) + wo] = bias[cc] + acc[cc];
}

// ---------------------------------------------------------------------------
extern "C" void kernel_launch(void* const* d_in, const int* in_sizes, int n_in,
                              void* d_out, int out_size, void* d_ws, size_t ws_size,
                              hipStream_t stream) {
  const float* x    = (const float*)d_in[0];
  const float* ew1  = (const float*)d_in[1];
  const float* eb1  = (const float*)d_in[2];
  const float* ew2  = (const float*)d_in[3];
  const float* eb2  = (const float*)d_in[4];
  const float* ew3  = (const float*)d_in[5];
  const float* eb3  = (const float*)d_in[6];
  const float* qw   = (const float*)d_in[7];
  const float* qb   = (const float*)d_in[8];
  const float* cb   = (const float*)d_in[9];
  const float* pw   = (const float*)d_in[10];
  const float* pb   = (const float*)d_in[11];
  const float* dw1  = (const float*)d_in[12];
  const float* db1  = (const float*)d_in[13];
  const float* dtw2 = (const float*)d_in[14];
  const float* dtb2 = (const float*)d_in[15];
  const float* dtw3 = (const float*)d_in[16];
  const float* dtb3 = (const float*)d_in[17];

  char* wsb = (char*)d_ws;
  float*    h1p  = (float*)(wsb + OFF_A);
  _Float16* Ap   = (_Float16*)(wsb + OFF_A);
  int4*     binfo= (int4*)(wsb + OFF_BINFO);
  _Float16* d2pH = (_Float16*)(wsb + OFF_A);
  float*    h2p  = (float*)(wsb + OFF_B);
  _Float16* qH   = (_Float16*)(wsb + OFF_B);
  float*    xpad = (float*)(wsb + OFF_C);
  float*    h3   = (float*)(wsb + OFF_C);
  _Float16* d1pH = (_Float16*)(wsb + OFF_C);
  float*    zff  = (float*)(wsb + OFF_D);
  _Float16* Bp   = (_Float16*)(wsb + OFF_E);
  float*    PC   = (float*)(wsb + OFF_E);
  float*    znb  = (float*)(wsb + OFF_ZN);
  float*    cnb  = (float*)(wsb + OFF_CN);
  int*      idxb = (int*)(wsb + OFF_IDX);
  float*    accum= (float*)(wsb + OFF_ACC);
  _Float16* wh2  = (_Float16*)(wsb + OFF_WR2);
  _Float16* whd1 = (_Float16*)(wsb + OFF_WHD1);
  float*    wr3  = (float*)(wsb + OFF_WR3);
  float*    qwT  = (float*)(wsb + OFF_QWT);
  double*   wd2  = (double*)(wsb + OFF_WD2);
  double*   wd3  = (double*)(wsb + OFF_WD3);
  double*   wd1  = (double*)(wsb + OFF_WD1);

  float* out      = (float*)d_out;
  float* outLoss  = out + 786432;
  float* outIdxF  = out + 786433;

  // prep mega: weight reshapes/widens + pad zeros + padx interior copy
  hipLaunchKernelGGL(prep_k, dim3(6698), dim3(256), 0, stream,
                     dtw2, wh2, dtw3, wr3, qw, qwT, ew2, wd2, ew3, wd3,
                     ew1, wd1, dw1, whd1, x, xpad, h1p, h2p);

  // encoder: per-op fp32-rounded (f64-exact inside each op)
  hipLaunchKernelGGL(conv1_k,      dim3(4096),  dim3(256), 0, stream, xpad, wd1, eb1, h1p);
  hipLaunchKernelGGL(conv2_k,      dim3(1024),  dim3(256), 0, stream, h1p, wd2, eb2, h2p);
  hipLaunchKernelGGL(conv3_k,      dim3(1024),  dim3(256), 0, stream, h2p, wd3, eb3, h3);
  hipLaunchKernelGGL(qconv_mega_k, dim3(24576), dim3(256), 0, stream,
                     h3, qwT, qb, zff, Ap, znb, cb, Bp, cnb, accum);

  // VQ: fp16 K=256 MFMA filter + ILP-batched exact rescore (+commit, +pc)
  hipLaunchKernelGGL(vq_gemm_k, dim3(8192), dim3(256), 0, stream, Ap, Bp, cnb, binfo);
  hipLaunchKernelGGL(p3_mega_k, dim3(8192), dim3(256), 0, stream,
                     zff, cb, znb, cnb, binfo, idxb, accum, outIdxF, pw, PC);

  // decoder f16-MFMA (pqconv folded through codebook: q = PC[idx] + b)
  hipLaunchKernelGGL(gather_mega_k, dim3(9728), dim3(256), 0, stream,
                     PC, idxb, pb, qH, d1pH, d2pH);
  hipLaunchKernelGGL(dconv1_k, dim3(2048), dim3(256), 0, stream, qH, whd1, db1, d1pH);
  hipLaunchKernelGGL(convt2_k, dim3(8192), dim3(256), 0, stream, d1pH, wh2, dtb2, d2pH);
  hipLaunchKernelGGL(convt3_k, dim3(1024), dim3(256), 0, stream, d2pH, wr3, dtb3,
                     out, accum, outLoss);
}